// Round 1
// baseline (1749.133 us; speedup 1.0000x reference)
//
#include <hip/hip_runtime.h>
#include <hip/hip_bf16.h>
#include <math.h>

#define S_LEN 2048
#define DMODEL 1024
#define NH 16
#define MH 4
#define HD 64

// ---------------- fp32 tiled GEMM: C(M,N) = A(M,K) @ B(K,N), row-major ----------------
__global__ __launch_bounds__(256) void gemm_f32(
    const float* __restrict__ A, const float* __restrict__ B,
    float* __restrict__ C, int M, int N, int K)
{
  __shared__ float As[16][132];   // [k][m], padded: write banks 2-way, reads broadcast
  __shared__ float Bs[16][132];   // [k][n]
  const int t  = threadIdx.x;
  const int tx = t & 15;          // col group (8 cols each)
  const int ty = t >> 4;          // row group (8 rows each)
  const int bm = blockIdx.y * 128;
  const int bn = blockIdx.x * 128;

  float acc[8][8];
  #pragma unroll
  for (int i = 0; i < 8; i++)
    #pragma unroll
    for (int j = 0; j < 8; j++) acc[i][j] = 0.f;

  for (int k0 = 0; k0 < K; k0 += 16) {
    #pragma unroll
    for (int i = 0; i < 8; i++) {
      int idx = t + 256 * i;
      int m = idx >> 4, kk = idx & 15;
      As[kk][m] = A[(size_t)(bm + m) * K + k0 + kk];
    }
    #pragma unroll
    for (int i = 0; i < 8; i++) {
      int idx = t + 256 * i;
      int kk = idx >> 7, n = idx & 127;
      Bs[kk][n] = B[(size_t)(k0 + kk) * N + bn + n];
    }
    __syncthreads();
    #pragma unroll
    for (int kk = 0; kk < 16; kk++) {
      float ra[8], rb[8];
      #pragma unroll
      for (int i = 0; i < 8; i++) ra[i] = As[kk][ty * 8 + i];
      #pragma unroll
      for (int j = 0; j < 8; j++) rb[j] = Bs[kk][tx * 8 + j];
      #pragma unroll
      for (int i = 0; i < 8; i++)
        #pragma unroll
        for (int j = 0; j < 8; j++) acc[i][j] = fmaf(ra[i], rb[j], acc[i][j]);
    }
    __syncthreads();
  }
  #pragma unroll
  for (int i = 0; i < 8; i++) {
    size_t row = bm + ty * 8 + i;
    #pragma unroll
    for (int j = 0; j < 8; j++)
      C[row * N + bn + tx * 8 + j] = acc[i][j];
  }
}

// ---------------- prep: qk-norm + rope (in place), v mix, attn gates ----------------
__global__ __launch_bounds__(256) void prep_kernel(
    const float* __restrict__ x, const int* __restrict__ token_ids,
    const float* __restrict__ ve_embed, const float* __restrict__ ve_gate,
    const float* __restrict__ attn_gate, const float* __restrict__ vlam,
    const float* __restrict__ velam,
    float* __restrict__ q, float* __restrict__ k, float* __restrict__ v,
    float* __restrict__ ag)
{
  const int row  = blockIdx.x;        // b*S + s
  const int s    = row & (S_LEN - 1);
  const int t    = threadIdx.x;
  const int lane = t & 63;
  const int wave = t >> 6;

  __shared__ float xg[12];
  if (t < 12) xg[t] = x[(size_t)row * DMODEL + t];
  __syncthreads();

  // 20 head-tasks: 0..15 -> q heads, 16..19 -> k heads. One wave per task.
  #pragma unroll
  for (int it = 0; it < 5; ++it) {
    const int task = wave + 4 * it;
    float* ptr = (task < 16) ? (q + ((size_t)row * NH + task) * HD)
                             : (k + ((size_t)row * MH + (task - 16)) * HD);
    float val = ptr[lane];
    float ss = val * val;
    #pragma unroll
    for (int o = 32; o; o >>= 1) ss += __shfl_xor(ss, o);
    const float nv = val * rsqrtf(ss * (1.0f / 64.0f) + 1e-6f);
    const float partner = __shfl_xor(nv, 16);
    float out;
    if (lane < 32) {
      const int idx = lane & 15;
      const float ang = (float)s * exp2f(-0.625f * (float)idx); // 1/1024^(idx/16)
      float c, sn;
      sincosf(ang, &sn, &c);
      out = (lane < 16) ? (nv * c - partner * sn) : (nv * c + partner * sn);
    } else {
      out = nv;
    }
    ptr[lane] = out;
  }

  // v = vlam*v + velam * 2*sigmoid(x[:12]@ve_gate)[m] * ve_embed[token]
  const int m = t >> 6;
  float z = 0.f;
  #pragma unroll
  for (int i = 0; i < 12; ++i) z += xg[i] * ve_gate[i * MH + m];
  const float veg = 2.f / (1.f + __expf(-z));
  const int tok = token_ids[row];
  const size_t vi = (size_t)row * (MH * HD) + t;
  v[vi] = vlam[0] * v[vi] + velam[0] * veg * ve_embed[(size_t)tok * (MH * HD) + t];

  if (t < 16) {
    float z2 = 0.f;
    #pragma unroll
    for (int i = 0; i < 12; ++i) z2 += xg[i] * attn_gate[i * NH + t];
    ag[(size_t)row * NH + t] = 2.f / (1.f + __expf(-z2));
  }
}

// ---------------- causal GQA flash attention, fp32 ----------------
// grid (S/64, NH, B), 256 threads. 4 threads per q-row (16 dims each).
// attn may alias q: qreg loaded before first barrier, output stored after all barriers.
__global__ __launch_bounds__(256) void attn_kernel(
    const float* __restrict__ q, const float* __restrict__ k,
    const float* __restrict__ v, const float* __restrict__ ag,
    float* __restrict__ attn)
{
  const int qt = blockIdx.x;
  const int n  = blockIdx.y;
  const int b  = blockIdx.z;
  const int m  = n >> 2;           // G = 4
  const int t  = threadIdx.x;
  const int r  = t >> 2;           // q row within tile
  const int c4 = t & 3;            // dim quarter

  __shared__ float Ks[64][64];
  __shared__ float Vs[64][64];
  __shared__ float Ps[64][65];

  const int srow = qt * 64 + r;
  const float* qrow = q + (((size_t)b * S_LEN + srow) * NH + n) * HD;
  float qreg[64];
  #pragma unroll
  for (int d4 = 0; d4 < 16; d4++) {
    float4 qv = ((const float4*)qrow)[d4];
    qreg[4*d4+0] = qv.x; qreg[4*d4+1] = qv.y; qreg[4*d4+2] = qv.z; qreg[4*d4+3] = qv.w;
  }

  float O[16];
  #pragma unroll
  for (int j = 0; j < 16; j++) O[j] = 0.f;
  float m_run = -1e30f, l_run = 0.f;

  for (int kt = 0; kt <= qt; kt++) {
    __syncthreads();   // protect Ks/Vs from previous iteration's readers
    #pragma unroll
    for (int i = 0; i < 4; i++) {
      int idx = t + 256 * i;              // float4 index over 64x16
      int rr = idx >> 4, d4 = idx & 15;
      const size_t kvbase = (((size_t)b * S_LEN + kt * 64 + rr) * MH + m) * HD;
      ((float4*)Ks)[rr * 16 + d4] = ((const float4*)(k + kvbase))[d4];
      ((float4*)Vs)[rr * 16 + d4] = ((const float4*)(v + kvbase))[d4];
    }
    __syncthreads();

    float p[16];
    float mloc = -1e30f;
    #pragma unroll
    for (int i = 0; i < 16; i++) {
      const int kk = c4 * 16 + i;
      float s = 0.f;
      const float4* krow = (const float4*)&Ks[kk][0];
      #pragma unroll
      for (int d4 = 0; d4 < 16; d4++) {
        float4 kv = krow[d4];
        s = fmaf(qreg[4*d4+0], kv.x, s);
        s = fmaf(qreg[4*d4+1], kv.y, s);
        s = fmaf(qreg[4*d4+2], kv.z, s);
        s = fmaf(qreg[4*d4+3], kv.w, s);
      }
      s *= 0.125f;
      if (kt * 64 + kk > srow) s = -1e30f;   // causal mask
      p[i] = s;
      mloc = fmaxf(mloc, s);
    }
    mloc = fmaxf(mloc, __shfl_xor(mloc, 1));
    mloc = fmaxf(mloc, __shfl_xor(mloc, 2));
    const float m_new = fmaxf(m_run, mloc);
    float lloc = 0.f;
    #pragma unroll
    for (int i = 0; i < 16; i++) {
      float e = __expf(p[i] - m_new);
      Ps[r][c4 * 16 + i] = e;
      lloc += e;
    }
    lloc += __shfl_xor(lloc, 1);
    lloc += __shfl_xor(lloc, 2);
    const float alpha = __expf(m_run - m_new);
    m_run = m_new;
    l_run = l_run * alpha + lloc;
    #pragma unroll
    for (int j = 0; j < 16; j++) O[j] *= alpha;
    __syncthreads();   // Ps visible to row threads (cross-wave safety)

    #pragma unroll
    for (int kk = 0; kk < 64; kk++) {
      const float pv = Ps[r][kk];
      const float4* vrow = (const float4*)&Vs[kk][c4 * 16];
      #pragma unroll
      for (int j4 = 0; j4 < 4; j4++) {
        float4 vv = vrow[j4];
        O[4*j4+0] = fmaf(pv, vv.x, O[4*j4+0]);
        O[4*j4+1] = fmaf(pv, vv.y, O[4*j4+1]);
        O[4*j4+2] = fmaf(pv, vv.z, O[4*j4+2]);
        O[4*j4+3] = fmaf(pv, vv.w, O[4*j4+3]);
      }
    }
  }

  const float sc = ag[((size_t)b * S_LEN + srow) * NH + n] / l_run;
  float* orow = attn + (((size_t)b * S_LEN + srow) * NH + n) * HD + c4 * 16;
  #pragma unroll
  for (int j4 = 0; j4 < 4; j4++) {
    float4 ov;
    ov.x = O[4*j4+0] * sc; ov.y = O[4*j4+1] * sc;
    ov.z = O[4*j4+2] * sc; ov.w = O[4*j4+3] * sc;
    ((float4*)orow)[j4] = ov;
  }
}

extern "C" void kernel_launch(void* const* d_in, const int* in_sizes, int n_in,
                              void* d_out, int out_size, void* d_ws, size_t ws_size,
                              hipStream_t stream) {
  const float* x         = (const float*)d_in[0];
  const int*   token_ids = (const int*)d_in[1];
  // d_in[2] = mask (causal, known analytically) — unused
  const float* w_q       = (const float*)d_in[3];
  const float* w_k       = (const float*)d_in[4];
  const float* w_v       = (const float*)d_in[5];
  const float* w_o       = (const float*)d_in[6];
  const float* ve_embed  = (const float*)d_in[7];
  const float* vlam      = (const float*)d_in[8];
  const float* velam     = (const float*)d_in[9];
  const float* ve_gate   = (const float*)d_in[10];
  const float* attn_gate = (const float*)d_in[11];
  float* out = (float*)d_out;

  const int BS = 2 * S_LEN;  // 4096 rows
  float* ws     = (float*)d_ws;
  float* q_ws   = ws;                                 // BS*NH*HD = 4,194,304
  float* k_ws   = q_ws + (size_t)BS * NH * HD;        // BS*MH*HD = 1,048,576
  float* v_ws   = k_ws + (size_t)BS * MH * HD;        // 1,048,576
  float* ag_ws  = v_ws + (size_t)BS * MH * HD;        // BS*NH   =    65,536
  float* attn_ws = q_ws;  // safe alias: attn blocks read their q rows into regs
                          // before the first barrier and store after all barriers

  dim3 blk(256);
  gemm_f32<<<dim3(1024/128, BS/128), blk, 0, stream>>>(x, w_q, q_ws, BS, 1024, 1024);
  gemm_f32<<<dim3( 256/128, BS/128), blk, 0, stream>>>(x, w_k, k_ws, BS,  256, 1024);
  gemm_f32<<<dim3( 256/128, BS/128), blk, 0, stream>>>(x, w_v, v_ws, BS,  256, 1024);
  prep_kernel<<<dim3(BS), blk, 0, stream>>>(x, token_ids, ve_embed, ve_gate,
                                            attn_gate, vlam, velam,
                                            q_ws, k_ws, v_ws, ag_ws);
  attn_kernel<<<dim3(S_LEN/64, NH, 2), blk, 0, stream>>>(q_ws, k_ws, v_ws, ag_ws, attn_ws);
  gemm_f32<<<dim3(1024/128, BS/128), blk, 0, stream>>>(attn_ws, w_o, out, BS, 1024, 1024);
}

// Round 2
// 198.844 us; speedup vs baseline: 8.7965x; 8.7965x over previous
//
#include <hip/hip_runtime.h>
#include <math.h>

#define S_LEN 2048
#define NHEADS 16
#define KVH 4

typedef __attribute__((ext_vector_type(8))) _Float16 half8;
typedef __attribute__((ext_vector_type(4))) float f32x4;

// async global->LDS, 16B per lane. LDS dest = wave-uniform base + lane*16.
__device__ inline void gld16(const void* g, void* l) {
  __builtin_amdgcn_global_load_lds(
      (const __attribute__((address_space(1))) unsigned int*)g,
      (__attribute__((address_space(3))) unsigned int*)l, 16, 0, 0);
}

// ---------------- MFMA GEMM: C[M][N] = A[M][K] @ BT[N][K]^T ----------------
// 128x128 tile, BK=32, 4 waves (each 64x64 = 4x4 frags of 16x16).
// LDS layout: [row][32 k] f16, 4 slots of 8 f16 per row, slot XOR-swizzled by (row&3).
// AF32: A is fp32 (reg-staged + converted); else f16 via global_load_lds (pre-swizzled src).
template<typename OUT_T, bool AF32>
__global__ __launch_bounds__(256) void gemm_k(
    const void* __restrict__ Ap, const _Float16* __restrict__ BT,
    OUT_T* __restrict__ C, int M, int N, int K, int lda)
{
  __shared__ _Float16 As[4096];
  __shared__ _Float16 Bs[4096];
  const int t = threadIdx.x;
  const int w = t >> 6, l = t & 63;
  const int lg = l >> 4, ll = l & 15;
  const int bm = blockIdx.y * 128, bn = blockIdx.x * 128;
  const int wr = (w >> 1) * 64, wc = (w & 1) * 64;
  const int srow = t >> 2, sslot = t & 3;

  f32x4 acc[4][4] = {};

  for (int k0 = 0; k0 < K; k0 += 32) {
    __syncthreads();
    if (AF32) {
      const float* Af = (const float*)Ap;
      #pragma unroll
      for (int c = 0; c < 2; c++) {
        const int row = srow + c * 64;
        const float* src = Af + (size_t)(bm + row) * lda + k0 + ((sslot ^ (row & 3)) << 3);
        float4 f0 = *(const float4*)src;
        float4 f1 = *(const float4*)(src + 4);
        half8 h;
        h[0] = (_Float16)f0.x; h[1] = (_Float16)f0.y; h[2] = (_Float16)f0.z; h[3] = (_Float16)f0.w;
        h[4] = (_Float16)f1.x; h[5] = (_Float16)f1.y; h[6] = (_Float16)f1.z; h[7] = (_Float16)f1.w;
        *(half8*)((char*)As + row * 64 + sslot * 16) = h;   // linear dest = conflict-free
      }
    } else {
      const _Float16* Af = (const _Float16*)Ap;
      gld16(Af + (size_t)(bm + srow) * lda + k0 + ((sslot ^ (srow & 3)) << 3),
            (char*)As + w * 1024);
      gld16(Af + (size_t)(bm + srow + 64) * lda + k0 + ((sslot ^ (srow & 3)) << 3),
            (char*)As + 4096 + w * 1024);
    }
    gld16(BT + (size_t)(bn + srow) * K + k0 + ((sslot ^ (srow & 3)) << 3),
          (char*)Bs + w * 1024);
    gld16(BT + (size_t)(bn + srow + 64) * K + k0 + ((sslot ^ (srow & 3)) << 3),
          (char*)Bs + 4096 + w * 1024);
    __syncthreads();

    half8 af[4], bfr[4];
    #pragma unroll
    for (int mt = 0; mt < 4; mt++) {
      const int row = wr + mt * 16 + ll;
      af[mt] = *(const half8*)((const char*)As + row * 64 + ((lg ^ (row & 3)) << 4));
    }
    #pragma unroll
    for (int nt = 0; nt < 4; nt++) {
      const int row = wc + nt * 16 + ll;
      bfr[nt] = *(const half8*)((const char*)Bs + row * 64 + ((lg ^ (row & 3)) << 4));
    }
    #pragma unroll
    for (int mt = 0; mt < 4; mt++)
      #pragma unroll
      for (int nt = 0; nt < 4; nt++)
        acc[mt][nt] = __builtin_amdgcn_mfma_f32_16x16x32_f16(af[mt], bfr[nt], acc[mt][nt], 0, 0, 0);
  }

  // D layout (verified m89/m91): col = lane&15, row = (lane>>4)*4 + reg
  #pragma unroll
  for (int mt = 0; mt < 4; mt++) {
    #pragma unroll
    for (int r = 0; r < 4; r++) {
      const size_t row = (size_t)bm + wr + mt * 16 + lg * 4 + r;
      #pragma unroll
      for (int nt = 0; nt < 4; nt++) {
        const int col = bn + wc + nt * 16 + ll;
        if constexpr (sizeof(OUT_T) == 2) C[row * N + col] = (OUT_T)(_Float16)acc[mt][nt][r];
        else                              C[row * N + col] = acc[mt][nt][r];
      }
    }
  }
}

// ---------------- weight transpose + f32->f16: out[C][1024] = in[R=1024][C]^T ----------------
__global__ __launch_bounds__(256) void transpose_w(
    const float* __restrict__ in, int C, _Float16* __restrict__ out)
{
  __shared__ float Ls[64][65];
  const int ct = blockIdx.x * 64, rt = blockIdx.y * 64;
  const int t = threadIdx.x;
  {
    const int r = t >> 2, cs = (t & 3) << 4;
    const float* src = in + (size_t)(rt + r) * C + ct + cs;
    #pragma unroll
    for (int j = 0; j < 16; j += 4) {
      float4 v = *(const float4*)(src + j);
      Ls[r][cs + j] = v.x; Ls[r][cs + j + 1] = v.y;
      Ls[r][cs + j + 2] = v.z; Ls[r][cs + j + 3] = v.w;
    }
  }
  __syncthreads();
  {
    const int c = t >> 2, rs = (t & 3) << 4;
    half8 h0, h1;
    #pragma unroll
    for (int j = 0; j < 8; j++) h0[j] = (_Float16)Ls[rs + j][c];
    #pragma unroll
    for (int j = 0; j < 8; j++) h1[j] = (_Float16)Ls[rs + 8 + j][c];
    _Float16* dst = out + (size_t)(ct + c) * 1024 + rt + rs;
    *(half8*)dst = h0;
    *(half8*)(dst + 8) = h1;
  }
}

// ---------------- prep: qk-norm + rope (in place, q *= 0.125), v-mix, attn gates ----------------
__global__ __launch_bounds__(256) void prep_kernel(
    const float* __restrict__ x, const int* __restrict__ token_ids,
    const float* __restrict__ ve_embed, const float* __restrict__ ve_gate,
    const float* __restrict__ attn_gate, const float* __restrict__ vlam,
    const float* __restrict__ velam,
    _Float16* __restrict__ qkv, float* __restrict__ ag)
{
  const int row = blockIdx.x;
  const int s = row & (S_LEN - 1);
  const int t = threadIdx.x;
  const int lane = t & 63, wave = t >> 6;

  __shared__ float xg[12];
  if (t < 12) xg[t] = x[(size_t)row * 1024 + t];
  __syncthreads();

  #pragma unroll
  for (int it = 0; it < 5; ++it) {
    const int task = wave + 4 * it;   // 0..15 q heads, 16..19 k heads
    _Float16* ptr = qkv + (size_t)row * 1536 + (task < 16 ? task * 64 : 1024 + (task - 16) * 64);
    float val = (float)ptr[lane];
    float ss = val * val;
    #pragma unroll
    for (int o = 32; o; o >>= 1) ss += __shfl_xor(ss, o);
    float nv = val * rsqrtf(ss * (1.0f / 64.0f) + 1e-6f);
    const float partner = __shfl_xor(nv, 16);
    float outv;
    if (lane < 32) {
      const int idx = lane & 15;
      const float ang = (float)s * exp2f(-0.625f * (float)idx);  // 1/1024^(idx/16)
      float c, sn;
      sincosf(ang, &sn, &c);
      outv = (lane < 16) ? (nv * c - partner * sn) : (nv * c + partner * sn);
    } else outv = nv;
    if (task < 16) outv *= 0.125f;   // fold 1/sqrt(HD) into q
    ptr[lane] = (_Float16)outv;
  }

  const int m = t >> 6;
  float z = 0.f;
  #pragma unroll
  for (int i = 0; i < 12; ++i) z += xg[i] * ve_gate[i * KVH + m];
  const float veg = 2.f / (1.f + __expf(-z));
  const int tok = token_ids[row];
  _Float16* vp = qkv + (size_t)row * 1536 + 1280;
  vp[t] = (_Float16)(vlam[0] * (float)vp[t] + velam[0] * veg * ve_embed[(size_t)tok * 256 + t]);

  if (t < 16) {
    float z2 = 0.f;
    #pragma unroll
    for (int i = 0; i < 12; ++i) z2 += xg[i] * attn_gate[i * NHEADS + t];
    ag[(size_t)row * NHEADS + t] = 2.f / (1.f + __expf(-z2));
  }
}

// ---------------- V transpose per (b,m): [S][64] -> [64][S], f16 ----------------
__global__ __launch_bounds__(256) void vtrans(
    const _Float16* __restrict__ qkv, _Float16* __restrict__ vT)
{
  __shared__ _Float16 Ls[64][72];
  const int st = blockIdx.x * 64;
  const int bm = blockIdx.y;           // b*4 + m
  const int b = bm >> 2, m = bm & 3;
  const int t = threadIdx.x;
  {
    const int sr = t >> 2, ds = (t & 3) << 4;
    const _Float16* src = qkv + ((size_t)(b * S_LEN + st + sr)) * 1536 + 1280 + m * 64 + ds;
    half8 v0 = *(const half8*)src;
    half8 v1 = *(const half8*)(src + 8);
    #pragma unroll
    for (int j = 0; j < 8; j++) { Ls[sr][ds + j] = v0[j]; Ls[sr][ds + 8 + j] = v1[j]; }
  }
  __syncthreads();
  {
    const int dr = t >> 2, ssl = (t & 3) << 4;
    half8 o0, o1;
    #pragma unroll
    for (int j = 0; j < 8; j++) { o0[j] = Ls[ssl + j][dr]; o1[j] = Ls[ssl + 8 + j][dr]; }
    _Float16* dst = vT + ((size_t)bm * 64 + dr) * S_LEN + st + ssl;
    *(half8*)dst = o0;
    *(half8*)(dst + 8) = o1;
  }
}

// ---------------- MFMA flash attention (causal, GQA) ----------------
// grid (32, 16, 2). 4 waves x 16 q-rows. K/V^T tiles 64x64 f16 in LDS,
// staged via global_load_lds with pre-swizzled source (slot ^= row&7).
// Output written IN PLACE over the q columns of qkv (block-disjoint, reg-held Q).
__global__ __launch_bounds__(256) void attn_mfma(
    _Float16* __restrict__ qkv, const _Float16* __restrict__ vT,
    const float* __restrict__ ag)
{
  const int qt = 31 - (int)blockIdx.x;  // longest blocks first
  const int n = blockIdx.y, b = blockIdx.z, m = n >> 2;
  const int t = threadIdx.x, w = t >> 6, l = t & 63;
  const int lg = l >> 4, ll = l & 15;

  __shared__ _Float16 Ks[4096];
  __shared__ _Float16 Vs[4096];   // V^T tile: [64 d][64 k]
  __shared__ _Float16 Ps[4096];   // per-wave rows, no cross-wave sharing

  const size_t qbase = ((size_t)(b * S_LEN + qt * 64 + w * 16 + ll)) * 1536 + n * 64;
  const half8 qa0 = *(const half8*)(qkv + qbase + lg * 8);
  const half8 qa1 = *(const half8*)(qkv + qbase + 32 + lg * 8);

  f32x4 o[4] = {};
  float mrun[4], lrun[4];
  #pragma unroll
  for (int r = 0; r < 4; r++) { mrun[r] = -1e30f; lrun[r] = 0.f; }

  const int srow = t >> 3, sslot = t & 7;

  for (int kt = 0; kt <= qt; kt++) {
    __syncthreads();   // protect K/V LDS from previous iteration's readers
    {
      const size_t kg = ((size_t)(b * S_LEN + kt * 64 + srow)) * 1536 + 1024 + m * 64
                        + ((sslot ^ (srow & 7)) << 3);
      gld16(qkv + kg,                        (char*)Ks + w * 1024);
      gld16(qkv + kg + (size_t)32 * 1536,    (char*)Ks + 4096 + w * 1024);
      const size_t vg = ((size_t)((b * KVH + m) * 64 + srow)) * S_LEN + kt * 64
                        + ((sslot ^ (srow & 7)) << 3);
      gld16(vT + vg,                         (char*)Vs + w * 1024);
      gld16(vT + vg + (size_t)32 * S_LEN,    (char*)Vs + 4096 + w * 1024);
    }
    __syncthreads();   // compiler drains vmcnt before barrier

    // QK^T: sc[kf] = 16q x 16k frag (q rows = this wave's, k cols = kf*16..)
    f32x4 sc[4] = {};
    #pragma unroll
    for (int s = 0; s < 2; s++) {
      const half8 qa = s ? qa1 : qa0;
      #pragma unroll
      for (int kf = 0; kf < 4; kf++) {
        const int row = kf * 16 + ll;
        const half8 kb = *(const half8*)((const char*)Ks + row * 128
                          + ((((s << 2) + lg) ^ (row & 7)) << 4));
        sc[kf] = __builtin_amdgcn_mfma_f32_16x16x32_f16(qa, kb, sc[kf], 0, 0, 0);
      }
    }

    if (kt == qt) {   // causal mask on the diagonal tile
      #pragma unroll
      for (int kf = 0; kf < 4; kf++) {
        const int k = kf * 16 + ll;
        #pragma unroll
        for (int r = 0; r < 4; r++)
          if (k > w * 16 + lg * 4 + r) sc[kf][r] = -1e30f;
      }
    }

    // online softmax; row r of lane-group lg -> q = w*16 + lg*4 + r
    float al[4], lsum[4];
    #pragma unroll
    for (int r = 0; r < 4; r++) {
      float mx = fmaxf(fmaxf(sc[0][r], sc[1][r]), fmaxf(sc[2][r], sc[3][r]));
      mx = fmaxf(mx, __shfl_xor(mx, 1));
      mx = fmaxf(mx, __shfl_xor(mx, 2));
      mx = fmaxf(mx, __shfl_xor(mx, 4));
      mx = fmaxf(mx, __shfl_xor(mx, 8));
      const float mn = fmaxf(mrun[r], mx);
      al[r] = __expf(mrun[r] - mn);
      mrun[r] = mn;
      lsum[r] = 0.f;
    }
    #pragma unroll
    for (int kf = 0; kf < 4; kf++) {
      const int k = kf * 16 + ll;
      #pragma unroll
      for (int r = 0; r < 4; r++) {
        const float e = __expf(sc[kf][r] - mrun[r]);
        lsum[r] += e;
        const int q = w * 16 + lg * 4 + r;
        Ps[q * 64 + ((((k >> 3) ^ (q & 7)) << 3) | (k & 7))] = (_Float16)e;
      }
    }
    #pragma unroll
    for (int r = 0; r < 4; r++) {
      float ls = lsum[r];
      ls += __shfl_xor(ls, 1);
      ls += __shfl_xor(ls, 2);
      ls += __shfl_xor(ls, 4);
      ls += __shfl_xor(ls, 8);
      lrun[r] = lrun[r] * al[r] + ls;
      o[0][r] *= al[r]; o[1][r] *= al[r]; o[2][r] *= al[r]; o[3][r] *= al[r];
    }

    // PV: o[df] += P(16q x 32k) * V^T(16d x 32k)^T  (wave-internal LDS RAW, lockstep-safe)
    #pragma unroll
    for (int s = 0; s < 2; s++) {
      const int prow = w * 16 + ll;
      const half8 pa = *(const half8*)((const char*)Ps + prow * 128
                        + ((((s << 2) + lg) ^ (prow & 7)) << 4));
      #pragma unroll
      for (int df = 0; df < 4; df++) {
        const int vrow = df * 16 + ll;
        const half8 vb = *(const half8*)((const char*)Vs + vrow * 128
                          + ((((s << 2) + lg) ^ (vrow & 7)) << 4));
        o[df] = __builtin_amdgcn_mfma_f32_16x16x32_f16(pa, vb, o[df], 0, 0, 0);
      }
    }
  }

  // epilogue: gate/normalize, write over own q columns (disjoint across blocks)
  #pragma unroll
  for (int r = 0; r < 4; r++) {
    const size_t qrow = (size_t)(b * S_LEN) + qt * 64 + w * 16 + lg * 4 + r;
    const float scale = ag[qrow * NHEADS + n] / lrun[r];
    #pragma unroll
    for (int df = 0; df < 4; df++)
      qkv[qrow * 1536 + n * 64 + df * 16 + ll] = (_Float16)(o[df][r] * scale);
  }
}

extern "C" void kernel_launch(void* const* d_in, const int* in_sizes, int n_in,
                              void* d_out, int out_size, void* d_ws, size_t ws_size,
                              hipStream_t stream) {
  const float* x         = (const float*)d_in[0];
  const int*   token_ids = (const int*)d_in[1];
  // d_in[2] = mask (causal, analytic) — unused
  const float* w_q       = (const float*)d_in[3];
  const float* w_k       = (const float*)d_in[4];
  const float* w_v       = (const float*)d_in[5];
  const float* w_o       = (const float*)d_in[6];
  const float* ve_embed  = (const float*)d_in[7];
  const float* vlam      = (const float*)d_in[8];
  const float* velam     = (const float*)d_in[9];
  const float* ve_gate   = (const float*)d_in[10];
  const float* attn_gate = (const float*)d_in[11];
  float* out = (float*)d_out;

  // workspace carve-up (20.2 MB total)
  char* p = (char*)d_ws;
  _Float16* wqkvT = (_Float16*)p; p += (size_t)1536 * 1024 * 2;  // 3.1 MB  [1536][1024] = [wq|wk|wv]^T
  _Float16* woT   = (_Float16*)p; p += (size_t)1024 * 1024 * 2;  // 2.1 MB
  _Float16* qkv   = (_Float16*)p; p += (size_t)4096 * 1536 * 2;  // 12.6 MB [B*S][q 1024 | k 256 | v 256]
  _Float16* vTb   = (_Float16*)p; p += (size_t)8 * 64 * S_LEN * 2; // 2.1 MB [B*M][64][S]
  float*    ag    = (float*)p;    p += (size_t)4096 * NHEADS * 4;  // 0.26 MB

  dim3 blk(256);
  transpose_w<<<dim3(16, 16), blk, 0, stream>>>(w_q, 1024, wqkvT);
  transpose_w<<<dim3( 4, 16), blk, 0, stream>>>(w_k,  256, wqkvT + (size_t)1024 * 1024);
  transpose_w<<<dim3( 4, 16), blk, 0, stream>>>(w_v,  256, wqkvT + (size_t)1280 * 1024);
  transpose_w<<<dim3(16, 16), blk, 0, stream>>>(w_o, 1024, woT);

  gemm_k<_Float16, true><<<dim3(12, 32), blk, 0, stream>>>(
      (const void*)x, wqkvT, qkv, 4096, 1536, 1024, 1024);

  prep_kernel<<<dim3(4096), blk, 0, stream>>>(x, token_ids, ve_embed, ve_gate,
                                              attn_gate, vlam, velam, qkv, ag);
  vtrans<<<dim3(32, 8), blk, 0, stream>>>(qkv, vTb);
  attn_mfma<<<dim3(32, 16, 2), blk, 0, stream>>>(qkv, vTb, ag);

  gemm_k<float, false><<<dim3(8, 32), blk, 0, stream>>>(
      (const void*)qkv, woT, out, 4096, 1024, 1024, 1536);
}

// Round 3
// 181.100 us; speedup vs baseline: 9.6584x; 1.0980x over previous
//
#include <hip/hip_runtime.h>
#include <math.h>

#define S_LEN 2048
#define NHEADS 16
#define KVH 4

typedef __attribute__((ext_vector_type(8))) _Float16 half8;
typedef __attribute__((ext_vector_type(4))) _Float16 half4;
typedef __attribute__((ext_vector_type(4))) float f32x4;

// async global->LDS, 16B per lane. LDS dest = wave-uniform base + lane*16.
__device__ inline void gld16(const void* g, void* l) {
  __builtin_amdgcn_global_load_lds(
      (const __attribute__((address_space(1))) unsigned int*)g,
      (__attribute__((address_space(3))) unsigned int*)l, 16, 0, 0);
}

// ---------------- MFMA GEMM: C[M][N] = A[M][K] @ BT[N][K]^T ----------------
// 128x128 tile, BK=32, 4 waves (each 64x64 = 4x4 frags of 16x16).
// LDS layout: [row][32 k] f16, 4 slots of 8 f16 per row, slot XOR-swizzled by (row&3).
// AF32: A is fp32 (reg-staged + converted); else f16 via global_load_lds (pre-swizzled src).
template<typename OUT_T, bool AF32>
__global__ __launch_bounds__(256) void gemm_k(
    const void* __restrict__ Ap, const _Float16* __restrict__ BT,
    OUT_T* __restrict__ C, int M, int N, int K, int lda)
{
  __shared__ _Float16 As[4096];
  __shared__ _Float16 Bs[4096];
  const int t = threadIdx.x;
  const int w = t >> 6, l = t & 63;
  const int lg = l >> 4, ll = l & 15;
  const int bm = blockIdx.y * 128, bn = blockIdx.x * 128;
  const int wr = (w >> 1) * 64, wc = (w & 1) * 64;
  const int srow = t >> 2, sslot = t & 3;

  f32x4 acc[4][4] = {};

  for (int k0 = 0; k0 < K; k0 += 32) {
    __syncthreads();
    if (AF32) {
      const float* Af = (const float*)Ap;
      #pragma unroll
      for (int c = 0; c < 2; c++) {
        const int row = srow + c * 64;
        const float* src = Af + (size_t)(bm + row) * lda + k0 + ((sslot ^ (row & 3)) << 3);
        float4 f0 = *(const float4*)src;
        float4 f1 = *(const float4*)(src + 4);
        half8 h;
        h[0] = (_Float16)f0.x; h[1] = (_Float16)f0.y; h[2] = (_Float16)f0.z; h[3] = (_Float16)f0.w;
        h[4] = (_Float16)f1.x; h[5] = (_Float16)f1.y; h[6] = (_Float16)f1.z; h[7] = (_Float16)f1.w;
        *(half8*)((char*)As + row * 64 + sslot * 16) = h;   // linear dest = conflict-free
      }
    } else {
      const _Float16* Af = (const _Float16*)Ap;
      gld16(Af + (size_t)(bm + srow) * lda + k0 + ((sslot ^ (srow & 3)) << 3),
            (char*)As + w * 1024);
      gld16(Af + (size_t)(bm + srow + 64) * lda + k0 + ((sslot ^ (srow & 3)) << 3),
            (char*)As + 4096 + w * 1024);
    }
    gld16(BT + (size_t)(bn + srow) * K + k0 + ((sslot ^ (srow & 3)) << 3),
          (char*)Bs + w * 1024);
    gld16(BT + (size_t)(bn + srow + 64) * K + k0 + ((sslot ^ (srow & 3)) << 3),
          (char*)Bs + 4096 + w * 1024);
    __syncthreads();

    half8 af[4], bfr[4];
    #pragma unroll
    for (int mt = 0; mt < 4; mt++) {
      const int row = wr + mt * 16 + ll;
      af[mt] = *(const half8*)((const char*)As + row * 64 + ((lg ^ (row & 3)) << 4));
    }
    #pragma unroll
    for (int nt = 0; nt < 4; nt++) {
      const int row = wc + nt * 16 + ll;
      bfr[nt] = *(const half8*)((const char*)Bs + row * 64 + ((lg ^ (row & 3)) << 4));
    }
    #pragma unroll
    for (int mt = 0; mt < 4; mt++)
      #pragma unroll
      for (int nt = 0; nt < 4; nt++)
        acc[mt][nt] = __builtin_amdgcn_mfma_f32_16x16x32_f16(af[mt], bfr[nt], acc[mt][nt], 0, 0, 0);
  }

  // D layout (verified m89/m91): col = lane&15, row = (lane>>4)*4 + reg
  #pragma unroll
  for (int mt = 0; mt < 4; mt++) {
    #pragma unroll
    for (int r = 0; r < 4; r++) {
      const size_t row = (size_t)bm + wr + mt * 16 + lg * 4 + r;
      #pragma unroll
      for (int nt = 0; nt < 4; nt++) {
        const int col = bn + wc + nt * 16 + ll;
        if constexpr (sizeof(OUT_T) == 2) C[row * N + col] = (OUT_T)(_Float16)acc[mt][nt][r];
        else                              C[row * N + col] = acc[mt][nt][r];
      }
    }
  }
}

// ---------------- weight transpose + f32->f16: out[C][1024] = in[R=1024][C]^T ----------------
__global__ __launch_bounds__(256) void transpose_w(
    const float* __restrict__ in, int C, _Float16* __restrict__ out)
{
  __shared__ float Ls[64][65];
  const int ct = blockIdx.x * 64, rt = blockIdx.y * 64;
  const int t = threadIdx.x;
  {
    const int r = t >> 2, cs = (t & 3) << 4;
    const float* src = in + (size_t)(rt + r) * C + ct + cs;
    #pragma unroll
    for (int j = 0; j < 16; j += 4) {
      float4 v = *(const float4*)(src + j);
      Ls[r][cs + j] = v.x; Ls[r][cs + j + 1] = v.y;
      Ls[r][cs + j + 2] = v.z; Ls[r][cs + j + 3] = v.w;
    }
  }
  __syncthreads();
  {
    const int c = t >> 2, rs = (t & 3) << 4;
    half8 h0, h1;
    #pragma unroll
    for (int j = 0; j < 8; j++) h0[j] = (_Float16)Ls[rs + j][c];
    #pragma unroll
    for (int j = 0; j < 8; j++) h1[j] = (_Float16)Ls[rs + 8 + j][c];
    _Float16* dst = out + (size_t)(ct + c) * 1024 + rt + rs;
    *(half8*)dst = h0;
    *(half8*)(dst + 8) = h1;
  }
}

// ---------------- prep: qk-norm + rope (in place), v-mix, attn gates ----------------
// q additionally scaled by 0.125*log2(e) so attention works in the exp2 domain.
__global__ __launch_bounds__(256) void prep_kernel(
    const float* __restrict__ x, const int* __restrict__ token_ids,
    const float* __restrict__ ve_embed, const float* __restrict__ ve_gate,
    const float* __restrict__ attn_gate, const float* __restrict__ vlam,
    const float* __restrict__ velam,
    _Float16* __restrict__ qkv, float* __restrict__ ag)
{
  const int row = blockIdx.x;
  const int s = row & (S_LEN - 1);
  const int t = threadIdx.x;
  const int lane = t & 63, wave = t >> 6;

  __shared__ float xg[12];
  if (t < 12) xg[t] = x[(size_t)row * 1024 + t];
  __syncthreads();

  #pragma unroll
  for (int it = 0; it < 5; ++it) {
    const int task = wave + 4 * it;   // 0..15 q heads, 16..19 k heads
    _Float16* ptr = qkv + (size_t)row * 1536 + (task < 16 ? task * 64 : 1024 + (task - 16) * 64);
    float val = (float)ptr[lane];
    float ss = val * val;
    #pragma unroll
    for (int o = 32; o; o >>= 1) ss += __shfl_xor(ss, o);
    float nv = val * rsqrtf(ss * (1.0f / 64.0f) + 1e-6f);
    const float partner = __shfl_xor(nv, 16);
    float outv;
    if (lane < 32) {
      const int idx = lane & 15;
      const float ang = (float)s * exp2f(-0.625f * (float)idx);  // 1/1024^(idx/16)
      float c, sn;
      sincosf(ang, &sn, &c);
      outv = (lane < 16) ? (nv * c - partner * sn) : (nv * c + partner * sn);
    } else outv = nv;
    if (task < 16) outv *= 0.18033688f;   // 1/sqrt(HD) * log2(e) folded into q
    ptr[lane] = (_Float16)outv;
  }

  const int m = t >> 6;
  float z = 0.f;
  #pragma unroll
  for (int i = 0; i < 12; ++i) z += xg[i] * ve_gate[i * KVH + m];
  const float veg = 2.f / (1.f + __expf(-z));
  const int tok = token_ids[row];
  _Float16* vp = qkv + (size_t)row * 1536 + 1280;
  vp[t] = (_Float16)(vlam[0] * (float)vp[t] + velam[0] * veg * ve_embed[(size_t)tok * 256 + t]);

  if (t < 16) {
    float z2 = 0.f;
    #pragma unroll
    for (int i = 0; i < 12; ++i) z2 += xg[i] * attn_gate[i * NHEADS + t];
    ag[(size_t)row * NHEADS + t] = 2.f / (1.f + __expf(-z2));
  }
}

// ---------------- V transpose per (b,m): [S][64] -> [64][S], f16 ----------------
__global__ __launch_bounds__(256) void vtrans(
    const _Float16* __restrict__ qkv, _Float16* __restrict__ vT)
{
  __shared__ _Float16 Ls[64][72];
  const int st = blockIdx.x * 64;
  const int bm = blockIdx.y;           // b*4 + m
  const int b = bm >> 2, m = bm & 3;
  const int t = threadIdx.x;
  {
    const int sr = t >> 2, ds = (t & 3) << 4;
    const _Float16* src = qkv + ((size_t)(b * S_LEN + st + sr)) * 1536 + 1280 + m * 64 + ds;
    half8 v0 = *(const half8*)src;
    half8 v1 = *(const half8*)(src + 8);
    #pragma unroll
    for (int j = 0; j < 8; j++) { Ls[sr][ds + j] = v0[j]; Ls[sr][ds + 8 + j] = v1[j]; }
  }
  __syncthreads();
  {
    const int dr = t >> 2, ssl = (t & 3) << 4;
    half8 o0, o1;
    #pragma unroll
    for (int j = 0; j < 8; j++) { o0[j] = Ls[ssl + j][dr]; o1[j] = Ls[ssl + 8 + j][dr]; }
    _Float16* dst = vT + ((size_t)bm * 64 + dr) * S_LEN + st + ssl;
    *(half8*)dst = o0;
    *(half8*)(dst + 8) = o1;
  }
}

// ---------------- MFMA flash attention (causal, GQA), swapped-QK softmax ----------------
// grid (32, 16, 2). 4 waves x 16 q-rows, KV tile = 128.
// Swapped QK^T: sc = mfma(K, Q) -> lane holds q = lane&15, k = lg*4+reg (+16*kf).
// Softmax per-lane (one q per lane): local max/sum + 2 shfl. exp2 domain.
// Output written IN PLACE over the q columns of qkv (block-disjoint, reg-held Q).
__global__ __launch_bounds__(256) void attn_mfma(
    _Float16* __restrict__ qkv, const _Float16* __restrict__ vT,
    const float* __restrict__ ag)
{
  const int qt = 31 - (int)blockIdx.x;  // longest blocks first
  const int n = blockIdx.y, b = blockIdx.z, m = n >> 2;
  const int t = threadIdx.x, w = t >> 6, l = t & 63;
  const int lg = l >> 4, ll = l & 15;

  __shared__ _Float16 Ks[128 * 64];   // [128 k][64 d], 8x16B slots/row, slot^=(row&7)
  __shared__ _Float16 Vs[64 * 128];   // [64 d][128 k], 16 slots/row, slot^=(row&7)
  __shared__ _Float16 Ps[64 * 128];   // [64 q][128 k], per-wave rows, slot^=(row&7)

  const size_t qbase = ((size_t)(b * S_LEN + qt * 64 + w * 16 + ll)) * 1536 + n * 64;
  const half8 qa0 = *(const half8*)(qkv + qbase + lg * 8);
  const half8 qa1 = *(const half8*)(qkv + qbase + 32 + lg * 8);

  f32x4 o[4] = {};
  float mrun = -1e30f, lrun = 0.f;     // per-lane state for q-row = w*16 + ll

  const int krow_s = l >> 3, kslot_s = l & 7;    // K staging: 8 rows/wave
  const int vrow_s = l >> 4, vslot_s = l & 15;   // V staging: 4 rows/wave
  const int qg = qt * 64 + w * 16 + ll;          // this lane's global q row

  const int nkt = (qt + 2) >> 1;
  for (int kt = 0; kt < nkt; kt++) {
    __syncthreads();   // protect K/V LDS from previous iteration's readers
    #pragma unroll
    for (int c = 0; c < 4; c++) {
      const int kr = w * 8 + c * 32 + krow_s;
      const size_t kg = ((size_t)(b * S_LEN + kt * 128 + kr)) * 1536 + 1024 + m * 64
                        + ((kslot_s ^ (kr & 7)) << 3);
      gld16(qkv + kg, (char*)Ks + c * 4096 + w * 1024);
      const int vr = w * 4 + c * 16 + vrow_s;
      const size_t vg = ((size_t)((b * KVH + m) * 64 + vr)) * S_LEN + kt * 128
                        + ((vslot_s ^ (vr & 7)) << 3);
      gld16(vT + vg, (char*)Vs + c * 4096 + w * 1024);
    }
    __syncthreads();   // compiler drains vmcnt before barrier

    // QK^T (swapped): sc[kf] rows = k (16 per frag), cols = q
    f32x4 sc[8] = {};
    __builtin_amdgcn_s_setprio(1);
    #pragma unroll
    for (int s = 0; s < 2; s++) {
      const half8 qa = s ? qa1 : qa0;
      #pragma unroll
      for (int kf = 0; kf < 8; kf++) {
        const int row = kf * 16 + ll;
        const half8 kb = *(const half8*)((const char*)Ks + row * 128
                          + (((s * 4 + lg) ^ (row & 7)) << 4));
        sc[kf] = __builtin_amdgcn_mfma_f32_16x16x32_f16(kb, qa, sc[kf], 0, 0, 0);
      }
    }
    __builtin_amdgcn_s_setprio(0);

    if (kt == nkt - 1) {   // diagonal block: causal mask (k > q -> -inf)
      const int kb0 = kt * 128 + lg * 4;
      #pragma unroll
      for (int kf = 0; kf < 8; kf++)
        #pragma unroll
        for (int r = 0; r < 4; r++)
          if (kb0 + kf * 16 + r > qg) sc[kf][r] = -1e30f;
    }

    // per-lane row max over 32 local values + 2 shfl
    float pmx = -1e30f;
    #pragma unroll
    for (int kf = 0; kf < 8; kf++)
      pmx = fmaxf(pmx, fmaxf(fmaxf(sc[kf][0], sc[kf][1]), fmaxf(sc[kf][2], sc[kf][3])));
    pmx = fmaxf(pmx, __shfl_xor(pmx, 16));
    pmx = fmaxf(pmx, __shfl_xor(pmx, 32));

    // defer-max (T13): only rescale when tile max grows by > 8 (log2 domain)
    if (!__all(pmx <= mrun + 8.0f)) {
      const float mnew = fmaxf(mrun, pmx);
      const float al = exp2f(mrun - mnew);
      mrun = mnew;
      lrun *= al;
      float alr[4];
      #pragma unroll
      for (int r = 0; r < 4; r++) alr[r] = __shfl(al, lg * 4 + r);
      #pragma unroll
      for (int df = 0; df < 4; df++)
        #pragma unroll
        for (int r = 0; r < 4; r++) o[df][r] *= alr[r];
    }

    // P = exp2(sc - mrun); pack 4 f16 per ds_write_b64 into swizzled Ps
    float ls = 0.f;
    const int prow = w * 16 + ll;
    #pragma unroll
    for (int kf = 0; kf < 8; kf++) {
      half4 pk;
      #pragma unroll
      for (int r = 0; r < 4; r++) {
        const float e = exp2f(sc[kf][r] - mrun);
        ls += e;
        pk[r] = (_Float16)e;
      }
      const int slot = (2 * kf + (lg >> 1)) ^ (prow & 7);
      *(half4*)((char*)Ps + prow * 256 + slot * 16 + (lg & 1) * 8) = pk;
    }
    ls += __shfl_xor(ls, 16);
    ls += __shfl_xor(ls, 32);
    lrun += ls;

    // PV: o[df] += P(16q x 32k) * V (wave-internal LDS RAW, in-order per wave)
    __builtin_amdgcn_s_setprio(1);
    #pragma unroll
    for (int s = 0; s < 4; s++) {
      const half8 pa = *(const half8*)((const char*)Ps + prow * 256
                        + (((s * 4 + lg) ^ (prow & 7)) << 4));
      #pragma unroll
      for (int df = 0; df < 4; df++) {
        const int vrow = df * 16 + ll;
        const half8 vb = *(const half8*)((const char*)Vs + vrow * 256
                          + (((s * 4 + lg) ^ (vrow & 7)) << 4));
        o[df] = __builtin_amdgcn_mfma_f32_16x16x32_f16(pa, vb, o[df], 0, 0, 0);
      }
    }
    __builtin_amdgcn_s_setprio(0);
  }

  // epilogue: gate/normalize, write over own q columns (disjoint across blocks)
  float lr[4];
  #pragma unroll
  for (int r = 0; r < 4; r++) lr[r] = __shfl(lrun, lg * 4 + r);
  #pragma unroll
  for (int r = 0; r < 4; r++) {
    const size_t qrow = (size_t)(b * S_LEN) + qt * 64 + w * 16 + lg * 4 + r;
    const float scale = ag[qrow * NHEADS + n] / lr[r];
    #pragma unroll
    for (int df = 0; df < 4; df++)
      qkv[qrow * 1536 + n * 64 + df * 16 + ll] = (_Float16)(o[df][r] * scale);
  }
}

extern "C" void kernel_launch(void* const* d_in, const int* in_sizes, int n_in,
                              void* d_out, int out_size, void* d_ws, size_t ws_size,
                              hipStream_t stream) {
  const float* x         = (const float*)d_in[0];
  const int*   token_ids = (const int*)d_in[1];
  // d_in[2] = mask (causal, analytic) — unused
  const float* w_q       = (const float*)d_in[3];
  const float* w_k       = (const float*)d_in[4];
  const float* w_v       = (const float*)d_in[5];
  const float* w_o       = (const float*)d_in[6];
  const float* ve_embed  = (const float*)d_in[7];
  const float* vlam      = (const float*)d_in[8];
  const float* velam     = (const float*)d_in[9];
  const float* ve_gate   = (const float*)d_in[10];
  const float* attn_gate = (const float*)d_in[11];
  float* out = (float*)d_out;

  // workspace carve-up (20.2 MB total)
  char* p = (char*)d_ws;
  _Float16* wqkvT = (_Float16*)p; p += (size_t)1536 * 1024 * 2;    // [wq|wk|wv]^T
  _Float16* woT   = (_Float16*)p; p += (size_t)1024 * 1024 * 2;
  _Float16* qkv   = (_Float16*)p; p += (size_t)4096 * 1536 * 2;    // [B*S][q1024|k256|v256]
  _Float16* vTb   = (_Float16*)p; p += (size_t)8 * 64 * S_LEN * 2; // [B*M][64][S]
  float*    ag    = (float*)p;    p += (size_t)4096 * NHEADS * 4;

  dim3 blk(256);
  transpose_w<<<dim3(16, 16), blk, 0, stream>>>(w_q, 1024, wqkvT);
  transpose_w<<<dim3( 4, 16), blk, 0, stream>>>(w_k,  256, wqkvT + (size_t)1024 * 1024);
  transpose_w<<<dim3( 4, 16), blk, 0, stream>>>(w_v,  256, wqkvT + (size_t)1280 * 1024);
  transpose_w<<<dim3(16, 16), blk, 0, stream>>>(w_o, 1024, woT);

  gemm_k<_Float16, true><<<dim3(12, 32), blk, 0, stream>>>(
      (const void*)x, wqkvT, qkv, 4096, 1536, 1024, 1024);

  prep_kernel<<<dim3(4096), blk, 0, stream>>>(x, token_ids, ve_embed, ve_gate,
                                              attn_gate, vlam, velam, qkv, ag);
  vtrans<<<dim3(32, 8), blk, 0, stream>>>(qkv, vTb);
  attn_mfma<<<dim3(32, 16, 2), blk, 0, stream>>>(qkv, vTb, ag);

  gemm_k<float, false><<<dim3(8, 32), blk, 0, stream>>>(
      (const void*)qkv, woT, out, 4096, 1024, 1024, 1536);
}

// Round 5
// 157.256 us; speedup vs baseline: 11.1228x; 1.1516x over previous
//
#include <hip/hip_runtime.h>
#include <math.h>

#define S_LEN 2048
#define NHEADS 16
#define KVH 4

typedef __attribute__((ext_vector_type(8))) _Float16 half8;
typedef __attribute__((ext_vector_type(4))) _Float16 half4;
typedef __attribute__((ext_vector_type(4))) float f32x4;

// async global->LDS, 16B per lane. LDS dest = wave-uniform base + lane*16.
__device__ inline void gld16(const void* g, void* l) {
  __builtin_amdgcn_global_load_lds(
      (const __attribute__((address_space(1))) unsigned int*)g,
      (__attribute__((address_space(3))) unsigned int*)l, 16, 0, 0);
}

// ---------------- MFMA GEMM: C[M][N] = A[M][K] @ BT[N][K]^T ----------------
// 128x128 tile, BK=32, 4 waves (each 64x64 = 4x4 frags of 16x16).
// LDS layout: [row][32 k] f16, 4 slots of 8 f16 per row, slot XOR-swizzled by (row&3).
// AF32: A is fp32 (reg-staged + converted); else f16 via global_load_lds (pre-swizzled src).
template<typename OUT_T, bool AF32>
__global__ __launch_bounds__(256) void gemm_k(
    const void* __restrict__ Ap, const _Float16* __restrict__ BT,
    OUT_T* __restrict__ C, int M, int N, int K, int lda)
{
  __shared__ _Float16 As[4096];
  __shared__ _Float16 Bs[4096];
  const int t = threadIdx.x;
  const int w = t >> 6, l = t & 63;
  const int lg = l >> 4, ll = l & 15;
  const int bm = blockIdx.y * 128, bn = blockIdx.x * 128;
  const int wr = (w >> 1) * 64, wc = (w & 1) * 64;
  const int srow = t >> 2, sslot = t & 3;

  f32x4 acc[4][4] = {};

  for (int k0 = 0; k0 < K; k0 += 32) {
    __syncthreads();
    if (AF32) {
      const float* Af = (const float*)Ap;
      #pragma unroll
      for (int c = 0; c < 2; c++) {
        const int row = srow + c * 64;
        const float* src = Af + (size_t)(bm + row) * lda + k0 + ((sslot ^ (row & 3)) << 3);
        float4 f0 = *(const float4*)src;
        float4 f1 = *(const float4*)(src + 4);
        half8 h;
        h[0] = (_Float16)f0.x; h[1] = (_Float16)f0.y; h[2] = (_Float16)f0.z; h[3] = (_Float16)f0.w;
        h[4] = (_Float16)f1.x; h[5] = (_Float16)f1.y; h[6] = (_Float16)f1.z; h[7] = (_Float16)f1.w;
        *(half8*)((char*)As + row * 64 + sslot * 16) = h;   // linear dest = conflict-free
      }
    } else {
      const _Float16* Af = (const _Float16*)Ap;
      gld16(Af + (size_t)(bm + srow) * lda + k0 + ((sslot ^ (srow & 3)) << 3),
            (char*)As + w * 1024);
      gld16(Af + (size_t)(bm + srow + 64) * lda + k0 + ((sslot ^ (srow & 3)) << 3),
            (char*)As + 4096 + w * 1024);
    }
    gld16(BT + (size_t)(bn + srow) * K + k0 + ((sslot ^ (srow & 3)) << 3),
          (char*)Bs + w * 1024);
    gld16(BT + (size_t)(bn + srow + 64) * K + k0 + ((sslot ^ (srow & 3)) << 3),
          (char*)Bs + 4096 + w * 1024);
    __syncthreads();

    half8 af[4], bfr[4];
    #pragma unroll
    for (int mt = 0; mt < 4; mt++) {
      const int row = wr + mt * 16 + ll;
      af[mt] = *(const half8*)((const char*)As + row * 64 + ((lg ^ (row & 3)) << 4));
    }
    #pragma unroll
    for (int nt = 0; nt < 4; nt++) {
      const int row = wc + nt * 16 + ll;
      bfr[nt] = *(const half8*)((const char*)Bs + row * 64 + ((lg ^ (row & 3)) << 4));
    }
    #pragma unroll
    for (int mt = 0; mt < 4; mt++)
      #pragma unroll
      for (int nt = 0; nt < 4; nt++)
        acc[mt][nt] = __builtin_amdgcn_mfma_f32_16x16x32_f16(af[mt], bfr[nt], acc[mt][nt], 0, 0, 0);
  }

  // D layout: col = lane&15, row = (lane>>4)*4 + reg
  #pragma unroll
  for (int mt = 0; mt < 4; mt++) {
    #pragma unroll
    for (int r = 0; r < 4; r++) {
      const size_t row = (size_t)bm + wr + mt * 16 + lg * 4 + r;
      #pragma unroll
      for (int nt = 0; nt < 4; nt++) {
        const int col = bn + wc + nt * 16 + ll;
        if constexpr (sizeof(OUT_T) == 2) C[row * N + col] = (OUT_T)(_Float16)acc[mt][nt][r];
        else                              C[row * N + col] = acc[mt][nt][r];
      }
    }
  }
}

// ---------------- fused weight transposes + f32->f16 ----------------
// out[C][1024] = in[1024][C]^T for wq, wk, wv, wo. 640 blocks.
__global__ __launch_bounds__(256) void transpose_all(
    const float* __restrict__ wq, const float* __restrict__ wk,
    const float* __restrict__ wv, const float* __restrict__ wo,
    _Float16* __restrict__ wqkvT, _Float16* __restrict__ woT)
{
  int L = blockIdx.x;
  const float* in; _Float16* out; int C, ct, rt;
  if (L < 256)      { in = wq; out = wqkvT;                       C = 1024; ct = (L & 15) * 64; rt = (L >> 4) * 64; }
  else if (L < 320) { L -= 256; in = wk; out = wqkvT + (size_t)1024 * 1024; C = 256; ct = (L & 3) * 64; rt = (L >> 2) * 64; }
  else if (L < 384) { L -= 320; in = wv; out = wqkvT + (size_t)1280 * 1024; C = 256; ct = (L & 3) * 64; rt = (L >> 2) * 64; }
  else              { L -= 384; in = wo; out = woT;               C = 1024; ct = (L & 15) * 64; rt = (L >> 4) * 64; }

  __shared__ float Ls[64][65];
  const int t = threadIdx.x;
  {
    const int r = t >> 2, cs = (t & 3) << 4;
    const float* src = in + (size_t)(rt + r) * C + ct + cs;
    #pragma unroll
    for (int j = 0; j < 16; j += 4) {
      float4 v = *(const float4*)(src + j);
      Ls[r][cs + j] = v.x; Ls[r][cs + j + 1] = v.y;
      Ls[r][cs + j + 2] = v.z; Ls[r][cs + j + 3] = v.w;
    }
  }
  __syncthreads();
  {
    const int c = t >> 2, rs = (t & 3) << 4;
    half8 h0, h1;
    #pragma unroll
    for (int j = 0; j < 8; j++) h0[j] = (_Float16)Ls[rs + j][c];
    #pragma unroll
    for (int j = 0; j < 8; j++) h1[j] = (_Float16)Ls[rs + 8 + j][c];
    _Float16* dst = out + (size_t)(ct + c) * 1024 + rt + rs;
    *(half8*)dst = h0;
    *(half8*)(dst + 8) = h1;
  }
}

// ---------------- prep: qk-norm + rope (in place), v-mix, attn gates ----------------
// q additionally scaled by 0.125*log2(e) so attention works in the exp2 domain.
__global__ __launch_bounds__(256) void prep_kernel(
    const float* __restrict__ x, const int* __restrict__ token_ids,
    const float* __restrict__ ve_embed, const float* __restrict__ ve_gate,
    const float* __restrict__ attn_gate, const float* __restrict__ vlam,
    const float* __restrict__ velam,
    _Float16* __restrict__ qkv, float* __restrict__ ag)
{
  const int row = blockIdx.x;
  const int s = row & (S_LEN - 1);
  const int t = threadIdx.x;
  const int lane = t & 63, wave = t >> 6;

  __shared__ float xg[12];
  if (t < 12) xg[t] = x[(size_t)row * 1024 + t];
  __syncthreads();

  #pragma unroll
  for (int it = 0; it < 5; ++it) {
    const int task = wave + 4 * it;   // 0..15 q heads, 16..19 k heads
    _Float16* ptr = qkv + (size_t)row * 1536 + (task < 16 ? task * 64 : 1024 + (task - 16) * 64);
    float val = (float)ptr[lane];
    float ss = val * val;
    #pragma unroll
    for (int o = 32; o; o >>= 1) ss += __shfl_xor(ss, o);
    float nv = val * rsqrtf(ss * (1.0f / 64.0f) + 1e-6f);
    const float partner = __shfl_xor(nv, 16);
    float outv;
    if (lane < 32) {
      const int idx = lane & 15;
      const float ang = (float)s * exp2f(-0.625f * (float)idx);  // 1/1024^(idx/16)
      float c, sn;
      sincosf(ang, &sn, &c);
      outv = (lane < 16) ? (nv * c - partner * sn) : (nv * c + partner * sn);
    } else outv = nv;
    if (task < 16) outv *= 0.18033688f;   // 1/sqrt(HD) * log2(e) folded into q
    ptr[lane] = (_Float16)outv;
  }

  const int m = t >> 6;
  float z = 0.f;
  #pragma unroll
  for (int i = 0; i < 12; ++i) z += xg[i] * ve_gate[i * KVH + m];
  const float veg = 2.f / (1.f + __expf(-z));
  const int tok = token_ids[row];
  _Float16* vp = qkv + (size_t)row * 1536 + 1280;
  vp[t] = (_Float16)(vlam[0] * (float)vp[t] + velam[0] * veg * ve_embed[(size_t)tok * 256 + t]);

  if (t < 16) {
    float z2 = 0.f;
    #pragma unroll
    for (int i = 0; i < 12; ++i) z2 += xg[i] * attn_gate[i * NHEADS + t];
    ag[(size_t)row * NHEADS + t] = 2.f / (1.f + __expf(-z2));
  }
}

// ---------------- V transpose per (b,m): [S][64] -> [64][S], f16 ----------------
__global__ __launch_bounds__(256) void vtrans(
    const _Float16* __restrict__ qkv, _Float16* __restrict__ vT)
{
  __shared__ _Float16 Ls[64][72];
  const int st = blockIdx.x * 64;
  const int bm = blockIdx.y;           // b*4 + m
  const int b = bm >> 2, m = bm & 3;
  const int t = threadIdx.x;
  {
    const int sr = t >> 2, ds = (t & 3) << 4;
    const _Float16* src = qkv + ((size_t)(b * S_LEN + st + sr)) * 1536 + 1280 + m * 64 + ds;
    half8 v0 = *(const half8*)src;
    half8 v1 = *(const half8*)(src + 8);
    #pragma unroll
    for (int j = 0; j < 8; j++) { Ls[sr][ds + j] = v0[j]; Ls[sr][ds + 8 + j] = v1[j]; }
  }
  __syncthreads();
  {
    const int dr = t >> 2, ssl = (t & 3) << 4;
    half8 o0, o1;
    #pragma unroll
    for (int j = 0; j < 8; j++) { o0[j] = Ls[ssl + j][dr]; o1[j] = Ls[ssl + 8 + j][dr]; }
    _Float16* dst = vT + ((size_t)bm * 64 + dr) * S_LEN + st + ssl;
    *(half8*)dst = o0;
    *(half8*)(dst + 8) = o1;
  }
}

// ---------------- MFMA flash attention (causal, GQA) ----------------
// 512 blocks (1D, balance-paired decode), 4 waves x 32 q-rows (QBLK=128), KVBLK=64.
// K/V double-buffered in LDS, staged via gld16 with pre-swizzled source BEFORE compute
// (1 barrier/tile, load latency hidden under previous tile's compute).
// Swapped QK^T: sc = mfma(K, Q) -> lane holds q = lane&15, k = lg*4+reg. exp2 domain.
// Output written IN PLACE over the q columns of qkv (block-disjoint rows/head).
__global__ __launch_bounds__(256) void attn_mfma(
    _Float16* __restrict__ qkv, const _Float16* __restrict__ vT,
    const float* __restrict__ ag)
{
  // balanced decode: CU gets blocks L and L+256 with qt summing to 15
  const int L = blockIdx.x;
  const int half = L >> 8, idx = L & 255;
  const int n = idx & 15;
  const int qt = half ? (idx >> 4) : 15 - (idx >> 4);
  const int b = half;
  const int m = n >> 2;

  const int t = threadIdx.x, w = t >> 6, l = t & 63;
  const int lg = l >> 4, ll = l & 15;

  // LDS map (48 KB): [0,8K) = K buf0/1, [8K,16K) = V buf0/1, [16K,32K) = Ps
  // (byte offsets; no LDS pointer arrays — addrspacecast init is unsupported)
  __shared__ _Float16 lds[24576];

  const int qbase = qt * 128 + w * 32;                // wave's first q row
  const size_t qrow_g = (size_t)(b * S_LEN) + qbase;

  // Q frags: qa[qf][s] — B-operand rows = q (ll), elems d = s*32 + lg*8
  half8 qa[2][2];
  #pragma unroll
  for (int qf = 0; qf < 2; qf++)
    #pragma unroll
    for (int s = 0; s < 2; s++)
      qa[qf][s] = *(const half8*)(qkv + (qrow_g + qf * 16 + ll) * 1536 + n * 64 + s * 32 + lg * 8);

  f32x4 o[2][4] = {};
  float mrun[2] = {-1e30f, -1e30f}, lrun[2] = {0.f, 0.f};

  const int srow = l >> 3, sslot = l & 7;   // staging: lane covers (row l>>3, slot l&7)
  const int nkt = 2 * qt + 2;

  auto stage = [&](int kt, int buf) {
    #pragma unroll
    for (int i = 0; i < 2; i++) {
      const int kr = w * 16 + i * 8 + srow;           // local k row 0..63
      const size_t kg = ((size_t)(b * S_LEN + kt * 64 + kr)) * 1536 + 1024 + m * 64
                        + ((sslot ^ (kr & 7)) << 3);
      gld16(qkv + kg, (char*)lds + buf * 8192 + w * 2048 + i * 1024);
      const int vr = w * 16 + i * 8 + srow;           // local d row 0..63
      const size_t vg = ((size_t)((b * KVH + m) * 64 + vr)) * S_LEN + kt * 64
                        + ((sslot ^ (vr & 7)) << 3);
      gld16(vT + vg, (char*)lds + 16384 + buf * 8192 + w * 2048 + i * 1024);
    }
  };

  stage(0, 0);
  __syncthreads();

  for (int kt = 0; kt < nkt; kt++) {
    const int cur = kt & 1;
    if (kt + 1 < nkt) stage(kt + 1, cur ^ 1);   // hide next tile's latency under compute

    if (kt * 64 <= qbase + 31) {                // skip fully-masked tiles for this wave
      const char* Ksb = (const char*)lds + cur * 8192;
      const char* Vsb = (const char*)lds + 16384 + cur * 8192;
      char* Psb = (char*)lds + 32768;

      #pragma unroll
      for (int qf = 0; qf < 2; qf++) {
        f32x4 sc[4] = {};
        __builtin_amdgcn_s_setprio(1);
        #pragma unroll
        for (int s = 0; s < 2; s++)
          #pragma unroll
          for (int kf = 0; kf < 4; kf++) {
            const int krow = kf * 16 + ll;
            const half8 kb = *(const half8*)(Ksb + krow * 128
                              + (((4 * s + lg) ^ (krow & 7)) << 4));
            sc[kf] = __builtin_amdgcn_mfma_f32_16x16x32_f16(kb, qa[qf][s], sc[kf], 0, 0, 0);
          }
        __builtin_amdgcn_s_setprio(0);

        const int qg = qbase + qf * 16 + ll;     // this lane's q row (global within seq)
        if (kt * 64 + 63 > qbase + qf * 16) {    // tile crosses diagonal for this frag
          #pragma unroll
          for (int kf = 0; kf < 4; kf++)
            #pragma unroll
            for (int r = 0; r < 4; r++)
              if (kt * 64 + kf * 16 + 4 * lg + r > qg) sc[kf][r] = -1e30f;
        }

        float pmx = -1e30f;
        #pragma unroll
        for (int kf = 0; kf < 4; kf++)
          pmx = fmaxf(pmx, fmaxf(fmaxf(sc[kf][0], sc[kf][1]), fmaxf(sc[kf][2], sc[kf][3])));
        pmx = fmaxf(pmx, __shfl_xor(pmx, 16));
        pmx = fmaxf(pmx, __shfl_xor(pmx, 32));

        // defer-max: rescale only when tile max grows by > 8 (log2 domain, P <= 256)
        if (!__all(pmx <= mrun[qf] + 8.0f)) {
          const float mnew = fmaxf(mrun[qf], pmx);
          const float al = exp2f(mrun[qf] - mnew);
          mrun[qf] = mnew;
          lrun[qf] *= al;
          float alr[4];
          #pragma unroll
          for (int r = 0; r < 4; r++) alr[r] = __shfl(al, lg * 4 + r);
          #pragma unroll
          for (int df = 0; df < 4; df++)
            #pragma unroll
            for (int r = 0; r < 4; r++) o[qf][df][r] *= alr[r];
        }

        float ls = 0.f;
        const int q_loc = w * 32 + qf * 16 + ll;
        #pragma unroll
        for (int kf = 0; kf < 4; kf++) {
          half4 pk;
          #pragma unroll
          for (int r = 0; r < 4; r++) {
            const float e = exp2f(sc[kf][r] - mrun[qf]);
            ls += e;
            pk[r] = (_Float16)e;
          }
          const int slot = (2 * kf + (lg >> 1)) ^ (q_loc & 7);
          *(half4*)(Psb + q_loc * 128 + slot * 16 + (lg & 1) * 8) = pk;
        }
        ls += __shfl_xor(ls, 16);
        ls += __shfl_xor(ls, 32);
        lrun[qf] += ls;
      }

      // PV: o[qf][df] += P(16q x 32k) * V^T frags (wave-local Ps, in-order per wave)
      __builtin_amdgcn_s_setprio(1);
      #pragma unroll
      for (int s = 0; s < 2; s++) {
        half8 pa[2];
        #pragma unroll
        for (int qf = 0; qf < 2; qf++) {
          const int prow = w * 32 + qf * 16 + ll;
          pa[qf] = *(const half8*)(Psb + prow * 128 + (((4 * s + lg) ^ (prow & 7)) << 4));
        }
        #pragma unroll
        for (int df = 0; df < 4; df++) {
          const int vrow = df * 16 + ll;
          const half8 vb = *(const half8*)(Vsb + vrow * 128
                            + (((4 * s + lg) ^ (vrow & 7)) << 4));
          o[0][df] = __builtin_amdgcn_mfma_f32_16x16x32_f16(pa[0], vb, o[0][df], 0, 0, 0);
          o[1][df] = __builtin_amdgcn_mfma_f32_16x16x32_f16(pa[1], vb, o[1][df], 0, 0, 0);
        }
      }
      __builtin_amdgcn_s_setprio(0);
    }

    __syncthreads();   // drains this wave's stage issues; guards buffer reuse
  }

  // epilogue: gate/normalize, write over own q columns (disjoint across blocks)
  #pragma unroll
  for (int qf = 0; qf < 2; qf++) {
    float lr[4];
    #pragma unroll
    for (int r = 0; r < 4; r++) lr[r] = __shfl(lrun[qf], lg * 4 + r);
    #pragma unroll
    for (int r = 0; r < 4; r++) {
      const size_t qrow = qrow_g + qf * 16 + lg * 4 + r;
      const float scale = ag[qrow * NHEADS + n] / lr[r];
      #pragma unroll
      for (int df = 0; df < 4; df++)
        qkv[qrow * 1536 + n * 64 + df * 16 + ll] = (_Float16)(o[qf][df][r] * scale);
    }
  }
}

extern "C" void kernel_launch(void* const* d_in, const int* in_sizes, int n_in,
                              void* d_out, int out_size, void* d_ws, size_t ws_size,
                              hipStream_t stream) {
  const float* x         = (const float*)d_in[0];
  const int*   token_ids = (const int*)d_in[1];
  // d_in[2] = mask (causal, analytic) — unused
  const float* w_q       = (const float*)d_in[3];
  const float* w_k       = (const float*)d_in[4];
  const float* w_v       = (const float*)d_in[5];
  const float* w_o       = (const float*)d_in[6];
  const float* ve_embed  = (const float*)d_in[7];
  const float* vlam      = (const float*)d_in[8];
  const float* velam     = (const float*)d_in[9];
  const float* ve_gate   = (const float*)d_in[10];
  const float* attn_gate = (const float*)d_in[11];
  float* out = (float*)d_out;

  // workspace carve-up (20.2 MB total)
  char* p = (char*)d_ws;
  _Float16* wqkvT = (_Float16*)p; p += (size_t)1536 * 1024 * 2;    // [wq|wk|wv]^T
  _Float16* woT   = (_Float16*)p; p += (size_t)1024 * 1024 * 2;
  _Float16* qkv   = (_Float16*)p; p += (size_t)4096 * 1536 * 2;    // [B*S][q1024|k256|v256]
  _Float16* vTb   = (_Float16*)p; p += (size_t)8 * 64 * S_LEN * 2; // [B*M][64][S]
  float*    ag    = (float*)p;    p += (size_t)4096 * NHEADS * 4;

  dim3 blk(256);
  transpose_all<<<dim3(640), blk, 0, stream>>>(w_q, w_k, w_v, w_o, wqkvT, woT);

  gemm_k<_Float16, true><<<dim3(12, 32), blk, 0, stream>>>(
      (const void*)x, wqkvT, qkv, 4096, 1536, 1024, 1024);

  prep_kernel<<<dim3(4096), blk, 0, stream>>>(x, token_ids, ve_embed, ve_gate,
                                              attn_gate, vlam, velam, qkv, ag);
  vtrans<<<dim3(32, 8), blk, 0, stream>>>(qkv, vTb);
  attn_mfma<<<dim3(512), blk, 0, stream>>>(qkv, vTb, ag);

  gemm_k<float, false><<<dim3(8, 32), blk, 0, stream>>>(
      (const void*)qkv, woT, out, 4096, 1024, 1024, 1536);
}

// Round 6
// 140.543 us; speedup vs baseline: 12.4455x; 1.1189x over previous
//
#include <hip/hip_runtime.h>
#include <math.h>

#define S_LEN 2048
#define NHEADS 16
#define KVH 4

typedef __attribute__((ext_vector_type(8))) _Float16 half8;
typedef __attribute__((ext_vector_type(4))) _Float16 half4;
typedef __attribute__((ext_vector_type(4))) float f32x4;

// async global->LDS, 16B per lane. LDS dest = wave-uniform base + lane*16.
__device__ inline void gld16(const void* g, void* l) {
  __builtin_amdgcn_global_load_lds(
      (const __attribute__((address_space(1))) unsigned int*)g,
      (__attribute__((address_space(3))) unsigned int*)l, 16, 0, 0);
}

// ---------------- MFMA GEMM: C[M][N] = A[M][K] @ BT[N][K]^T ----------------
// 128x128 tile, BK=32, 4 waves (each 64x64 = 4x4 frags of 16x16).
// LDS layout: [row][32 k] f16, 4 slots of 8 f16 per row, slot XOR-swizzled by (row&3).
// AF32: A is fp32 (reg-staged + converted); else f16 via global_load_lds (pre-swizzled src).
template<typename OUT_T, bool AF32>
__global__ __launch_bounds__(256) void gemm_k(
    const void* __restrict__ Ap, const _Float16* __restrict__ BT,
    OUT_T* __restrict__ C, int M, int N, int K, int lda)
{
  __shared__ _Float16 As[4096];
  __shared__ _Float16 Bs[4096];
  const int t = threadIdx.x;
  const int w = t >> 6, l = t & 63;
  const int lg = l >> 4, ll = l & 15;
  const int bm = blockIdx.y * 128, bn = blockIdx.x * 128;
  const int wr = (w >> 1) * 64, wc = (w & 1) * 64;
  const int srow = t >> 2, sslot = t & 3;

  f32x4 acc[4][4] = {};

  for (int k0 = 0; k0 < K; k0 += 32) {
    __syncthreads();
    if (AF32) {
      const float* Af = (const float*)Ap;
      #pragma unroll
      for (int c = 0; c < 2; c++) {
        const int row = srow + c * 64;
        const float* src = Af + (size_t)(bm + row) * lda + k0 + ((sslot ^ (row & 3)) << 3);
        float4 f0 = *(const float4*)src;
        float4 f1 = *(const float4*)(src + 4);
        half8 h;
        h[0] = (_Float16)f0.x; h[1] = (_Float16)f0.y; h[2] = (_Float16)f0.z; h[3] = (_Float16)f0.w;
        h[4] = (_Float16)f1.x; h[5] = (_Float16)f1.y; h[6] = (_Float16)f1.z; h[7] = (_Float16)f1.w;
        *(half8*)((char*)As + row * 64 + sslot * 16) = h;   // linear dest = conflict-free
      }
    } else {
      const _Float16* Af = (const _Float16*)Ap;
      gld16(Af + (size_t)(bm + srow) * lda + k0 + ((sslot ^ (srow & 3)) << 3),
            (char*)As + w * 1024);
      gld16(Af + (size_t)(bm + srow + 64) * lda + k0 + ((sslot ^ (srow & 3)) << 3),
            (char*)As + 4096 + w * 1024);
    }
    gld16(BT + (size_t)(bn + srow) * K + k0 + ((sslot ^ (srow & 3)) << 3),
          (char*)Bs + w * 1024);
    gld16(BT + (size_t)(bn + srow + 64) * K + k0 + ((sslot ^ (srow & 3)) << 3),
          (char*)Bs + 4096 + w * 1024);
    __syncthreads();

    half8 af[4], bfr[4];
    #pragma unroll
    for (int mt = 0; mt < 4; mt++) {
      const int row = wr + mt * 16 + ll;
      af[mt] = *(const half8*)((const char*)As + row * 64 + ((lg ^ (row & 3)) << 4));
    }
    #pragma unroll
    for (int nt = 0; nt < 4; nt++) {
      const int row = wc + nt * 16 + ll;
      bfr[nt] = *(const half8*)((const char*)Bs + row * 64 + ((lg ^ (row & 3)) << 4));
    }
    #pragma unroll
    for (int mt = 0; mt < 4; mt++)
      #pragma unroll
      for (int nt = 0; nt < 4; nt++)
        acc[mt][nt] = __builtin_amdgcn_mfma_f32_16x16x32_f16(af[mt], bfr[nt], acc[mt][nt], 0, 0, 0);
  }

  // D layout: col = lane&15, row = (lane>>4)*4 + reg
  #pragma unroll
  for (int mt = 0; mt < 4; mt++) {
    #pragma unroll
    for (int r = 0; r < 4; r++) {
      const size_t row = (size_t)bm + wr + mt * 16 + lg * 4 + r;
      #pragma unroll
      for (int nt = 0; nt < 4; nt++) {
        const int col = bn + wc + nt * 16 + ll;
        if constexpr (sizeof(OUT_T) == 2) C[row * N + col] = (OUT_T)(_Float16)acc[mt][nt][r];
        else                              C[row * N + col] = acc[mt][nt][r];
      }
    }
  }
}

// ---------------- fused weight transposes + f32->f16 ----------------
// out[C][1024] = in[1024][C]^T for wq, wk, wv, wo. 640 blocks.
__global__ __launch_bounds__(256) void transpose_all(
    const float* __restrict__ wq, const float* __restrict__ wk,
    const float* __restrict__ wv, const float* __restrict__ wo,
    _Float16* __restrict__ wqkvT, _Float16* __restrict__ woT)
{
  int L = blockIdx.x;
  const float* in; _Float16* out; int C, ct, rt;
  if (L < 256)      { in = wq; out = wqkvT;                       C = 1024; ct = (L & 15) * 64; rt = (L >> 4) * 64; }
  else if (L < 320) { L -= 256; in = wk; out = wqkvT + (size_t)1024 * 1024; C = 256; ct = (L & 3) * 64; rt = (L >> 2) * 64; }
  else if (L < 384) { L -= 320; in = wv; out = wqkvT + (size_t)1280 * 1024; C = 256; ct = (L & 3) * 64; rt = (L >> 2) * 64; }
  else              { L -= 384; in = wo; out = woT;               C = 1024; ct = (L & 15) * 64; rt = (L >> 4) * 64; }

  __shared__ float Ls[64][65];
  const int t = threadIdx.x;
  {
    const int r = t >> 2, cs = (t & 3) << 4;
    const float* src = in + (size_t)(rt + r) * C + ct + cs;
    #pragma unroll
    for (int j = 0; j < 16; j += 4) {
      float4 v = *(const float4*)(src + j);
      Ls[r][cs + j] = v.x; Ls[r][cs + j + 1] = v.y;
      Ls[r][cs + j + 2] = v.z; Ls[r][cs + j + 3] = v.w;
    }
  }
  __syncthreads();
  {
    const int c = t >> 2, rs = (t & 3) << 4;
    half8 h0, h1;
    #pragma unroll
    for (int j = 0; j < 8; j++) h0[j] = (_Float16)Ls[rs + j][c];
    #pragma unroll
    for (int j = 0; j < 8; j++) h1[j] = (_Float16)Ls[rs + 8 + j][c];
    _Float16* dst = out + (size_t)(ct + c) * 1024 + rt + rs;
    *(half8*)dst = h0;
    *(half8*)(dst + 8) = h1;
  }
}

// ---------------- prep: qk-norm + rope (in place), v-mix, attn gates ----------------
// q additionally scaled by 0.125*log2(e) so attention works in the exp2 domain.
__global__ __launch_bounds__(256) void prep_kernel(
    const float* __restrict__ x, const int* __restrict__ token_ids,
    const float* __restrict__ ve_embed, const float* __restrict__ ve_gate,
    const float* __restrict__ attn_gate, const float* __restrict__ vlam,
    const float* __restrict__ velam,
    _Float16* __restrict__ qkv, float* __restrict__ ag)
{
  const int row = blockIdx.x;
  const int s = row & (S_LEN - 1);
  const int t = threadIdx.x;
  const int lane = t & 63, wave = t >> 6;

  __shared__ float xg[12];
  if (t < 12) xg[t] = x[(size_t)row * 1024 + t];
  __syncthreads();

  #pragma unroll
  for (int it = 0; it < 5; ++it) {
    const int task = wave + 4 * it;   // 0..15 q heads, 16..19 k heads
    _Float16* ptr = qkv + (size_t)row * 1536 + (task < 16 ? task * 64 : 1024 + (task - 16) * 64);
    float val = (float)ptr[lane];
    float ss = val * val;
    #pragma unroll
    for (int o = 32; o; o >>= 1) ss += __shfl_xor(ss, o);
    float nv = val * rsqrtf(ss * (1.0f / 64.0f) + 1e-6f);
    const float partner = __shfl_xor(nv, 16);
    float outv;
    if (lane < 32) {
      const int idx = lane & 15;
      const float ang = (float)s * exp2f(-0.625f * (float)idx);  // 1/1024^(idx/16)
      float c, sn;
      sincosf(ang, &sn, &c);
      outv = (lane < 16) ? (nv * c - partner * sn) : (nv * c + partner * sn);
    } else outv = nv;
    if (task < 16) outv *= 0.18033688f;   // 1/sqrt(HD) * log2(e) folded into q
    ptr[lane] = (_Float16)outv;
  }

  const int m = t >> 6;
  float z = 0.f;
  #pragma unroll
  for (int i = 0; i < 12; ++i) z += xg[i] * ve_gate[i * KVH + m];
  const float veg = 2.f / (1.f + __expf(-z));
  const int tok = token_ids[row];
  _Float16* vp = qkv + (size_t)row * 1536 + 1280;
  vp[t] = (_Float16)(vlam[0] * (float)vp[t] + velam[0] * veg * ve_embed[(size_t)tok * 256 + t]);

  if (t < 16) {
    float z2 = 0.f;
    #pragma unroll
    for (int i = 0; i < 12; ++i) z2 += xg[i] * attn_gate[i * NHEADS + t];
    ag[(size_t)row * NHEADS + t] = 2.f / (1.f + __expf(-z2));
  }
}

// ---------------- V transpose per (b,m): [S][64] -> [64][S], f16 ----------------
__global__ __launch_bounds__(256) void vtrans(
    const _Float16* __restrict__ qkv, _Float16* __restrict__ vT)
{
  __shared__ _Float16 Ls[64][72];
  const int st = blockIdx.x * 64;
  const int bm = blockIdx.y;           // b*4 + m
  const int b = bm >> 2, m = bm & 3;
  const int t = threadIdx.x;
  {
    const int sr = t >> 2, ds = (t & 3) << 4;
    const _Float16* src = qkv + ((size_t)(b * S_LEN + st + sr)) * 1536 + 1280 + m * 64 + ds;
    half8 v0 = *(const half8*)src;
    half8 v1 = *(const half8*)(src + 8);
    #pragma unroll
    for (int j = 0; j < 8; j++) { Ls[sr][ds + j] = v0[j]; Ls[sr][ds + 8 + j] = v1[j]; }
  }
  __syncthreads();
  {
    const int dr = t >> 2, ssl = (t & 3) << 4;
    half8 o0, o1;
    #pragma unroll
    for (int j = 0; j < 8; j++) { o0[j] = Ls[ssl + j][dr]; o1[j] = Ls[ssl + 8 + j][dr]; }
    _Float16* dst = vT + ((size_t)bm * 64 + dr) * S_LEN + st + ssl;
    *(half8*)dst = o0;
    *(half8*)(dst + 8) = o1;
  }
}

// ---------------- MFMA flash attention (causal, GQA) ----------------
// 1024 blocks (1D), 4 waves x 16 q-rows (QBLK=64), KVBLK=64 double-buffered.
// Per-CU load is constant under round-robin dispatch: blocks {c,c+256,c+512,c+768}
// have tile counts summing to 62. LDS 40KB -> 4 blocks/CU (160KB, full residency).
// Swapped QK^T: sc = mfma(K, Q) -> lane holds q = lane&15, k = lg*4+reg. exp2 domain.
// Output written IN PLACE over the q columns of qkv (block-disjoint rows/head).
__global__ __launch_bounds__(256) void attn_mfma(
    _Float16* __restrict__ qkv, const _Float16* __restrict__ vT,
    const float* __restrict__ ag)
{
  const int L = blockIdx.x;
  const int b = L >> 9, idx = L & 511;
  const int n = idx & 15;
  const int j = idx >> 4;               // 0..31
  const int qt = b ? j : 31 - j;        // balance: complementary work per dispatch slot
  const int m = n >> 2;

  const int t = threadIdx.x, w = t >> 6, l = t & 63;
  const int lg = l >> 4, ll = l & 15;

  // LDS map (40 KB): [0,16K) = K buf0/1, [16K,32K) = V buf0/1, [32K,40K) = Ps
  __shared__ _Float16 lds[20480];

  const int qbase = qt * 64 + w * 16;                 // wave's first q row
  const size_t qrow_g = (size_t)(b * S_LEN) + qbase;

  // Q frags: qa[s] — B-operand rows = q (ll), elems d = s*32 + lg*8
  half8 qa[2];
  #pragma unroll
  for (int s = 0; s < 2; s++)
    qa[s] = *(const half8*)(qkv + (qrow_g + ll) * 1536 + n * 64 + s * 32 + lg * 8);

  f32x4 o[4] = {};
  float mrun = -1e30f, lrun = 0.f;

  const int srow = l >> 3, sslot = l & 7;   // staging: lane covers (row l>>3, slot l&7)

  auto stage = [&](int kt, int buf) {
    #pragma unroll
    for (int i = 0; i < 2; i++) {
      const int kr = w * 16 + i * 8 + srow;           // local k row 0..63
      const size_t kg = ((size_t)(b * S_LEN + kt * 64 + kr)) * 1536 + 1024 + m * 64
                        + ((sslot ^ (kr & 7)) << 3);
      gld16(qkv + kg, (char*)lds + buf * 8192 + w * 2048 + i * 1024);
      const int vr = w * 16 + i * 8 + srow;           // local d row 0..63
      const size_t vg = ((size_t)((b * KVH + m) * 64 + vr)) * S_LEN + kt * 64
                        + ((sslot ^ (vr & 7)) << 3);
      gld16(vT + vg, (char*)lds + 16384 + buf * 8192 + w * 2048 + i * 1024);
    }
  };

  stage(0, 0);
  __syncthreads();

  for (int kt = 0; kt <= qt; kt++) {
    const int cur = kt & 1;
    if (kt < qt) stage(kt + 1, cur ^ 1);   // hide next tile's latency under compute

    const char* Ksb = (const char*)lds + cur * 8192;
    const char* Vsb = (const char*)lds + 16384 + cur * 8192;
    char* Psb = (char*)lds + 32768;

    // QK^T (swapped): D rows = k (lg*4+reg), cols = q (ll)
    f32x4 sc[4] = {};
    __builtin_amdgcn_s_setprio(1);
    #pragma unroll
    for (int s = 0; s < 2; s++)
      #pragma unroll
      for (int kf = 0; kf < 4; kf++) {
        const int krow = kf * 16 + ll;
        const half8 kb = *(const half8*)(Ksb + krow * 128
                          + (((4 * s + lg) ^ (krow & 7)) << 4));
        sc[kf] = __builtin_amdgcn_mfma_f32_16x16x32_f16(kb, qa[s], sc[kf], 0, 0, 0);
      }
    __builtin_amdgcn_s_setprio(0);

    if (kt == qt) {   // diagonal tile: causal mask (k > q -> -inf)
      const int qg = qbase + ll;
      #pragma unroll
      for (int kf = 0; kf < 4; kf++)
        #pragma unroll
        for (int r = 0; r < 4; r++)
          if (kt * 64 + kf * 16 + 4 * lg + r > qg) sc[kf][r] = -1e30f;
    }

    // per-lane row max over 16 local values + 2 shfl
    float pmx = -1e30f;
    #pragma unroll
    for (int kf = 0; kf < 4; kf++)
      pmx = fmaxf(pmx, fmaxf(fmaxf(sc[kf][0], sc[kf][1]), fmaxf(sc[kf][2], sc[kf][3])));
    pmx = fmaxf(pmx, __shfl_xor(pmx, 16));
    pmx = fmaxf(pmx, __shfl_xor(pmx, 32));

    // defer-max: rescale only when tile max grows by > 8 (log2 domain, P <= 256)
    if (!__all(pmx <= mrun + 8.0f)) {
      const float mnew = fmaxf(mrun, pmx);
      const float al = exp2f(mrun - mnew);
      mrun = mnew;
      lrun *= al;
      float alr[4];
      #pragma unroll
      for (int r = 0; r < 4; r++) alr[r] = __shfl(al, lg * 4 + r);
      #pragma unroll
      for (int df = 0; df < 4; df++)
        #pragma unroll
        for (int r = 0; r < 4; r++) o[df][r] *= alr[r];
    }

    // P = exp2(sc - mrun); pack 4 f16 per ds_write_b64 into swizzled Ps
    float ls = 0.f;
    const int q_loc = w * 16 + ll;
    #pragma unroll
    for (int kf = 0; kf < 4; kf++) {
      half4 pk;
      #pragma unroll
      for (int r = 0; r < 4; r++) {
        const float e = exp2f(sc[kf][r] - mrun);
        ls += e;
        pk[r] = (_Float16)e;
      }
      const int slot = (2 * kf + (lg >> 1)) ^ (q_loc & 7);
      *(half4*)(Psb + q_loc * 128 + slot * 16 + (lg & 1) * 8) = pk;
    }
    ls += __shfl_xor(ls, 16);
    ls += __shfl_xor(ls, 32);
    lrun += ls;

    // PV: o[df] += P(16q x 32k) * V^T frags (wave-local Ps, in-order per wave)
    __builtin_amdgcn_s_setprio(1);
    #pragma unroll
    for (int s = 0; s < 2; s++) {
      const half8 pa = *(const half8*)(Psb + q_loc * 128
                        + (((4 * s + lg) ^ (q_loc & 7)) << 4));
      #pragma unroll
      for (int df = 0; df < 4; df++) {
        const int vrow = df * 16 + ll;
        const half8 vb = *(const half8*)(Vsb + vrow * 128
                          + (((4 * s + lg) ^ (vrow & 7)) << 4));
        o[df] = __builtin_amdgcn_mfma_f32_16x16x32_f16(pa, vb, o[df], 0, 0, 0);
      }
    }
    __builtin_amdgcn_s_setprio(0);

    __syncthreads();   // drains this wave's stage issues; guards buffer reuse
  }

  // epilogue: gate/normalize, write over own q columns (disjoint across blocks)
  float lr[4];
  #pragma unroll
  for (int r = 0; r < 4; r++) lr[r] = __shfl(lrun, lg * 4 + r);
  #pragma unroll
  for (int r = 0; r < 4; r++) {
    const size_t qrow = qrow_g + lg * 4 + r;
    const float scale = ag[qrow * NHEADS + n] / lr[r];
    #pragma unroll
    for (int df = 0; df < 4; df++)
      qkv[qrow * 1536 + n * 64 + df * 16 + ll] = (_Float16)(o[df][r] * scale);
  }
}

extern "C" void kernel_launch(void* const* d_in, const int* in_sizes, int n_in,
                              void* d_out, int out_size, void* d_ws, size_t ws_size,
                              hipStream_t stream) {
  const float* x         = (const float*)d_in[0];
  const int*   token_ids = (const int*)d_in[1];
  // d_in[2] = mask (causal, analytic) — unused
  const float* w_q       = (const float*)d_in[3];
  const float* w_k       = (const float*)d_in[4];
  const float* w_v       = (const float*)d_in[5];
  const float* w_o       = (const float*)d_in[6];
  const float* ve_embed  = (const float*)d_in[7];
  const float* vlam      = (const float*)d_in[8];
  const float* velam     = (const float*)d_in[9];
  const float* ve_gate   = (const float*)d_in[10];
  const float* attn_gate = (const float*)d_in[11];
  float* out = (float*)d_out;

  // workspace carve-up (20.2 MB total)
  char* p = (char*)d_ws;
  _Float16* wqkvT = (_Float16*)p; p += (size_t)1536 * 1024 * 2;    // [wq|wk|wv]^T
  _Float16* woT   = (_Float16*)p; p += (size_t)1024 * 1024 * 2;
  _Float16* qkv   = (_Float16*)p; p += (size_t)4096 * 1536 * 2;    // [B*S][q1024|k256|v256]
  _Float16* vTb   = (_Float16*)p; p += (size_t)8 * 64 * S_LEN * 2; // [B*M][64][S]
  float*    ag    = (float*)p;    p += (size_t)4096 * NHEADS * 4;

  dim3 blk(256);
  transpose_all<<<dim3(640), blk, 0, stream>>>(w_q, w_k, w_v, w_o, wqkvT, woT);

  gemm_k<_Float16, true><<<dim3(12, 32), blk, 0, stream>>>(
      (const void*)x, wqkvT, qkv, 4096, 1536, 1024, 1024);

  prep_kernel<<<dim3(4096), blk, 0, stream>>>(x, token_ids, ve_embed, ve_gate,
                                              attn_gate, vlam, velam, qkv, ag);
  vtrans<<<dim3(32, 8), blk, 0, stream>>>(qkv, vTb);
  attn_mfma<<<dim3(1024), blk, 0, stream>>>(qkv, vTb, ag);

  gemm_k<float, false><<<dim3(8, 32), blk, 0, stream>>>(
      (const void*)qkv, woT, out, 4096, 1024, 1024, 1536);
}

// Round 7
// 125.791 us; speedup vs baseline: 13.9051x; 1.1173x over previous
//
#include <hip/hip_runtime.h>
#include <math.h>

#define S_LEN 2048
#define NHEADS 16
#define KVH 4

typedef __attribute__((ext_vector_type(8))) _Float16 half8;
typedef __attribute__((ext_vector_type(4))) _Float16 half4;
typedef __attribute__((ext_vector_type(4))) float f32x4;

// async global->LDS, 16B per lane. LDS dest = wave-uniform base + lane*16.
__device__ inline void gld16(const void* g, void* l) {
  __builtin_amdgcn_global_load_lds(
      (const __attribute__((address_space(1))) unsigned int*)g,
      (__attribute__((address_space(3))) unsigned int*)l, 16, 0, 0);
}

// ---------------- x f32 -> f16 cast (scratch lives in d_out, dead before final GEMM) ----
__global__ __launch_bounds__(256) void xcast(
    const float* __restrict__ x, _Float16* __restrict__ xh)
{
  const size_t i = ((size_t)blockIdx.x * 256 + threadIdx.x) * 8;
  float4 f0 = *(const float4*)(x + i);
  float4 f1 = *(const float4*)(x + i + 4);
  half8 h;
  h[0] = (_Float16)f0.x; h[1] = (_Float16)f0.y; h[2] = (_Float16)f0.z; h[3] = (_Float16)f0.w;
  h[4] = (_Float16)f1.x; h[5] = (_Float16)f1.y; h[6] = (_Float16)f1.z; h[7] = (_Float16)f1.w;
  *(half8*)(xh + i) = h;
}

// ---------------- MFMA GEMM: C[M][N] = A[M][K] @ BT[N][K]^T, f16 inputs ----------------
// 128x128 tile, BK=32, 4 waves (each 64x64 = 4x4 frags of 16x16).
// Double-buffered LDS (32 KB), stage-before-compute, ONE barrier per K-step:
// iter i issues async gld16 for step i+1 into buf^1 while MFMAs read buf;
// the end-of-step barrier drains vmcnt (compiler) and guards buffer reuse.
// LDS row = 64 B (4 x 16B slots), slot XOR-swizzled by (row&3); source pre-swizzled.
template<typename OUT_T>
__global__ __launch_bounds__(256) void gemm_k(
    const _Float16* __restrict__ A, const _Float16* __restrict__ BT,
    OUT_T* __restrict__ C, int M, int N, int K, int lda)
{
  // bytes: A buf0 [0,8K), A buf1 [8K,16K), B buf0 [16K,24K), B buf1 [24K,32K)
  __shared__ _Float16 lds[16384];
  const int t = threadIdx.x;
  const int w = t >> 6, l = t & 63;
  const int lg = l >> 4, ll = l & 15;
  const int bm = blockIdx.y * 128, bn = blockIdx.x * 128;
  const int wr = (w >> 1) * 64, wc = (w & 1) * 64;
  const int srow = t >> 2, sslot = t & 3;

  f32x4 acc[4][4] = {};

  auto stage = [&](int k0, int buf) {
    char* Ab = (char*)lds + buf * 8192;
    char* Bb = (char*)lds + 16384 + buf * 8192;
    const int so = (sslot ^ (srow & 3)) << 3;
    gld16(A  + (size_t)(bm + srow)      * lda + k0 + so, Ab + w * 1024);
    gld16(A  + (size_t)(bm + srow + 64) * lda + k0 + so, Ab + 4096 + w * 1024);
    gld16(BT + (size_t)(bn + srow)      * K   + k0 + so, Bb + w * 1024);
    gld16(BT + (size_t)(bn + srow + 64) * K   + k0 + so, Bb + 4096 + w * 1024);
  };

  stage(0, 0);
  __syncthreads();

  int buf = 0;
  for (int k0 = 0; k0 < K; k0 += 32) {
    if (k0 + 32 < K) stage(k0 + 32, buf ^ 1);   // overlap next-tile loads with MFMAs

    const char* Ab = (const char*)lds + buf * 8192;
    const char* Bb = (const char*)lds + 16384 + buf * 8192;
    half8 af[4], bfr[4];
    #pragma unroll
    for (int mt = 0; mt < 4; mt++) {
      const int row = wr + mt * 16 + ll;
      af[mt] = *(const half8*)(Ab + row * 64 + ((lg ^ (row & 3)) << 4));
    }
    #pragma unroll
    for (int nt = 0; nt < 4; nt++) {
      const int row = wc + nt * 16 + ll;
      bfr[nt] = *(const half8*)(Bb + row * 64 + ((lg ^ (row & 3)) << 4));
    }
    __builtin_amdgcn_s_setprio(1);
    #pragma unroll
    for (int mt = 0; mt < 4; mt++)
      #pragma unroll
      for (int nt = 0; nt < 4; nt++)
        acc[mt][nt] = __builtin_amdgcn_mfma_f32_16x16x32_f16(af[mt], bfr[nt], acc[mt][nt], 0, 0, 0);
    __builtin_amdgcn_s_setprio(0);

    __syncthreads();   // drains this step's gld16s; guards buffer reuse
    buf ^= 1;
  }

  // D layout: col = lane&15, row = (lane>>4)*4 + reg
  #pragma unroll
  for (int mt = 0; mt < 4; mt++) {
    #pragma unroll
    for (int r = 0; r < 4; r++) {
      const size_t row = (size_t)bm + wr + mt * 16 + lg * 4 + r;
      #pragma unroll
      for (int nt = 0; nt < 4; nt++) {
        const int col = bn + wc + nt * 16 + ll;
        if constexpr (sizeof(OUT_T) == 2) C[row * N + col] = (OUT_T)(_Float16)acc[mt][nt][r];
        else                              C[row * N + col] = acc[mt][nt][r];
      }
    }
  }
}

// ---------------- fused weight transposes + f32->f16 ----------------
// out[C][1024] = in[1024][C]^T for wq, wk, wv, wo. 640 blocks.
__global__ __launch_bounds__(256) void transpose_all(
    const float* __restrict__ wq, const float* __restrict__ wk,
    const float* __restrict__ wv, const float* __restrict__ wo,
    _Float16* __restrict__ wqkvT, _Float16* __restrict__ woT)
{
  int L = blockIdx.x;
  const float* in; _Float16* out; int C, ct, rt;
  if (L < 256)      { in = wq; out = wqkvT;                       C = 1024; ct = (L & 15) * 64; rt = (L >> 4) * 64; }
  else if (L < 320) { L -= 256; in = wk; out = wqkvT + (size_t)1024 * 1024; C = 256; ct = (L & 3) * 64; rt = (L >> 2) * 64; }
  else if (L < 384) { L -= 320; in = wv; out = wqkvT + (size_t)1280 * 1024; C = 256; ct = (L & 3) * 64; rt = (L >> 2) * 64; }
  else              { L -= 384; in = wo; out = woT;               C = 1024; ct = (L & 15) * 64; rt = (L >> 4) * 64; }

  __shared__ float Ls[64][65];
  const int t = threadIdx.x;
  {
    const int r = t >> 2, cs = (t & 3) << 4;
    const float* src = in + (size_t)(rt + r) * C + ct + cs;
    #pragma unroll
    for (int j = 0; j < 16; j += 4) {
      float4 v = *(const float4*)(src + j);
      Ls[r][cs + j] = v.x; Ls[r][cs + j + 1] = v.y;
      Ls[r][cs + j + 2] = v.z; Ls[r][cs + j + 3] = v.w;
    }
  }
  __syncthreads();
  {
    const int c = t >> 2, rs = (t & 3) << 4;
    half8 h0, h1;
    #pragma unroll
    for (int j = 0; j < 8; j++) h0[j] = (_Float16)Ls[rs + j][c];
    #pragma unroll
    for (int j = 0; j < 8; j++) h1[j] = (_Float16)Ls[rs + 8 + j][c];
    _Float16* dst = out + (size_t)(ct + c) * 1024 + rt + rs;
    *(half8*)dst = h0;
    *(half8*)(dst + 8) = h1;
  }
}

// ---------------- prep: qk-norm + rope (in place), v-mix, attn gates ----------------
// q additionally scaled by 0.125*log2(e) so attention works in the exp2 domain.
__global__ __launch_bounds__(256) void prep_kernel(
    const float* __restrict__ x, const int* __restrict__ token_ids,
    const float* __restrict__ ve_embed, const float* __restrict__ ve_gate,
    const float* __restrict__ attn_gate, const float* __restrict__ vlam,
    const float* __restrict__ velam,
    _Float16* __restrict__ qkv, float* __restrict__ ag)
{
  const int row = blockIdx.x;
  const int s = row & (S_LEN - 1);
  const int t = threadIdx.x;
  const int lane = t & 63, wave = t >> 6;

  __shared__ float xg[12];
  if (t < 12) xg[t] = x[(size_t)row * 1024 + t];
  __syncthreads();

  #pragma unroll
  for (int it = 0; it < 5; ++it) {
    const int task = wave + 4 * it;   // 0..15 q heads, 16..19 k heads
    _Float16* ptr = qkv + (size_t)row * 1536 + (task < 16 ? task * 64 : 1024 + (task - 16) * 64);
    float val = (float)ptr[lane];
    float ss = val * val;
    #pragma unroll
    for (int o = 32; o; o >>= 1) ss += __shfl_xor(ss, o);
    float nv = val * rsqrtf(ss * (1.0f / 64.0f) + 1e-6f);
    const float partner = __shfl_xor(nv, 16);
    float outv;
    if (lane < 32) {
      const int idx = lane & 15;
      const float ang = (float)s * exp2f(-0.625f * (float)idx);  // 1/1024^(idx/16)
      float c, sn;
      sincosf(ang, &sn, &c);
      outv = (lane < 16) ? (nv * c - partner * sn) : (nv * c + partner * sn);
    } else outv = nv;
    if (task < 16) outv *= 0.18033688f;   // 1/sqrt(HD) * log2(e) folded into q
    ptr[lane] = (_Float16)outv;
  }

  const int m = t >> 6;
  float z = 0.f;
  #pragma unroll
  for (int i = 0; i < 12; ++i) z += xg[i] * ve_gate[i * KVH + m];
  const float veg = 2.f / (1.f + __expf(-z));
  const int tok = token_ids[row];
  _Float16* vp = qkv + (size_t)row * 1536 + 1280;
  vp[t] = (_Float16)(vlam[0] * (float)vp[t] + velam[0] * veg * ve_embed[(size_t)tok * 256 + t]);

  if (t < 16) {
    float z2 = 0.f;
    #pragma unroll
    for (int i = 0; i < 12; ++i) z2 += xg[i] * attn_gate[i * NHEADS + t];
    ag[(size_t)row * NHEADS + t] = 2.f / (1.f + __expf(-z2));
  }
}

// ---------------- V transpose per (b,m): [S][64] -> [64][S], f16 ----------------
__global__ __launch_bounds__(256) void vtrans(
    const _Float16* __restrict__ qkv, _Float16* __restrict__ vT)
{
  __shared__ _Float16 Ls[64][72];
  const int st = blockIdx.x * 64;
  const int bm = blockIdx.y;           // b*4 + m
  const int b = bm >> 2, m = bm & 3;
  const int t = threadIdx.x;
  {
    const int sr = t >> 2, ds = (t & 3) << 4;
    const _Float16* src = qkv + ((size_t)(b * S_LEN + st + sr)) * 1536 + 1280 + m * 64 + ds;
    half8 v0 = *(const half8*)src;
    half8 v1 = *(const half8*)(src + 8);
    #pragma unroll
    for (int j = 0; j < 8; j++) { Ls[sr][ds + j] = v0[j]; Ls[sr][ds + 8 + j] = v1[j]; }
  }
  __syncthreads();
  {
    const int dr = t >> 2, ssl = (t & 3) << 4;
    half8 o0, o1;
    #pragma unroll
    for (int j = 0; j < 8; j++) { o0[j] = Ls[ssl + j][dr]; o1[j] = Ls[ssl + 8 + j][dr]; }
    _Float16* dst = vT + ((size_t)bm * 64 + dr) * S_LEN + st + ssl;
    *(half8*)dst = o0;
    *(half8*)(dst + 8) = o1;
  }
}

// ---------------- MFMA flash attention (causal, GQA) ----------------
// 1024 blocks (1D), 4 waves x 16 q-rows (QBLK=64), KVBLK=64 double-buffered.
// Per-CU load is constant under round-robin dispatch. LDS 40KB -> 4 blocks/CU.
// Swapped QK^T: sc = mfma(K, Q) -> lane holds q = lane&15, k = lg*4+reg. exp2 domain.
// Output written IN PLACE over the q columns of qkv (block-disjoint rows/head).
__global__ __launch_bounds__(256) void attn_mfma(
    _Float16* __restrict__ qkv, const _Float16* __restrict__ vT,
    const float* __restrict__ ag)
{
  const int L = blockIdx.x;
  const int b = L >> 9, idx = L & 511;
  const int n = idx & 15;
  const int j = idx >> 4;               // 0..31
  const int qt = b ? j : 31 - j;        // balance: complementary work per dispatch slot
  const int m = n >> 2;

  const int t = threadIdx.x, w = t >> 6, l = t & 63;
  const int lg = l >> 4, ll = l & 15;

  // LDS map (40 KB): [0,16K) = K buf0/1, [16K,32K) = V buf0/1, [32K,40K) = Ps
  __shared__ _Float16 lds[20480];

  const int qbase = qt * 64 + w * 16;                 // wave's first q row
  const size_t qrow_g = (size_t)(b * S_LEN) + qbase;

  // Q frags: qa[s] — B-operand rows = q (ll), elems d = s*32 + lg*8
  half8 qa[2];
  #pragma unroll
  for (int s = 0; s < 2; s++)
    qa[s] = *(const half8*)(qkv + (qrow_g + ll) * 1536 + n * 64 + s * 32 + lg * 8);

  f32x4 o[4] = {};
  float mrun = -1e30f, lrun = 0.f;

  const int srow = l >> 3, sslot = l & 7;   // staging: lane covers (row l>>3, slot l&7)

  auto stage = [&](int kt, int buf) {
    #pragma unroll
    for (int i = 0; i < 2; i++) {
      const int kr = w * 16 + i * 8 + srow;           // local k row 0..63
      const size_t kg = ((size_t)(b * S_LEN + kt * 64 + kr)) * 1536 + 1024 + m * 64
                        + ((sslot ^ (kr & 7)) << 3);
      gld16(qkv + kg, (char*)lds + buf * 8192 + w * 2048 + i * 1024);
      const int vr = w * 16 + i * 8 + srow;           // local d row 0..63
      const size_t vg = ((size_t)((b * KVH + m) * 64 + vr)) * S_LEN + kt * 64
                        + ((sslot ^ (vr & 7)) << 3);
      gld16(vT + vg, (char*)lds + 16384 + buf * 8192 + w * 2048 + i * 1024);
    }
  };

  stage(0, 0);
  __syncthreads();

  for (int kt = 0; kt <= qt; kt++) {
    const int cur = kt & 1;
    if (kt < qt) stage(kt + 1, cur ^ 1);   // hide next tile's latency under compute

    const char* Ksb = (const char*)lds + cur * 8192;
    const char* Vsb = (const char*)lds + 16384 + cur * 8192;
    char* Psb = (char*)lds + 32768;

    // QK^T (swapped): D rows = k (lg*4+reg), cols = q (ll)
    f32x4 sc[4] = {};
    __builtin_amdgcn_s_setprio(1);
    #pragma unroll
    for (int s = 0; s < 2; s++)
      #pragma unroll
      for (int kf = 0; kf < 4; kf++) {
        const int krow = kf * 16 + ll;
        const half8 kb = *(const half8*)(Ksb + krow * 128
                          + (((4 * s + lg) ^ (krow & 7)) << 4));
        sc[kf] = __builtin_amdgcn_mfma_f32_16x16x32_f16(kb, qa[s], sc[kf], 0, 0, 0);
      }
    __builtin_amdgcn_s_setprio(0);

    if (kt == qt) {   // diagonal tile: causal mask (k > q -> -inf)
      const int qg = qbase + ll;
      #pragma unroll
      for (int kf = 0; kf < 4; kf++)
        #pragma unroll
        for (int r = 0; r < 4; r++)
          if (kt * 64 + kf * 16 + 4 * lg + r > qg) sc[kf][r] = -1e30f;
    }

    // per-lane row max over 16 local values + 2 shfl
    float pmx = -1e30f;
    #pragma unroll
    for (int kf = 0; kf < 4; kf++)
      pmx = fmaxf(pmx, fmaxf(fmaxf(sc[kf][0], sc[kf][1]), fmaxf(sc[kf][2], sc[kf][3])));
    pmx = fmaxf(pmx, __shfl_xor(pmx, 16));
    pmx = fmaxf(pmx, __shfl_xor(pmx, 32));

    // defer-max: rescale only when tile max grows by > 8 (log2 domain, P <= 256)
    if (!__all(pmx <= mrun + 8.0f)) {
      const float mnew = fmaxf(mrun, pmx);
      const float al = exp2f(mrun - mnew);
      mrun = mnew;
      lrun *= al;
      float alr[4];
      #pragma unroll
      for (int r = 0; r < 4; r++) alr[r] = __shfl(al, lg * 4 + r);
      #pragma unroll
      for (int df = 0; df < 4; df++)
        #pragma unroll
        for (int r = 0; r < 4; r++) o[df][r] *= alr[r];
    }

    // P = exp2(sc - mrun); pack 4 f16 per ds_write_b64 into swizzled Ps
    float ls = 0.f;
    const int q_loc = w * 16 + ll;
    #pragma unroll
    for (int kf = 0; kf < 4; kf++) {
      half4 pk;
      #pragma unroll
      for (int r = 0; r < 4; r++) {
        const float e = exp2f(sc[kf][r] - mrun);
        ls += e;
        pk[r] = (_Float16)e;
      }
      const int slot = (2 * kf + (lg >> 1)) ^ (q_loc & 7);
      *(half4*)(Psb + q_loc * 128 + slot * 16 + (lg & 1) * 8) = pk;
    }
    ls += __shfl_xor(ls, 16);
    ls += __shfl_xor(ls, 32);
    lrun += ls;

    // PV: o[df] += P(16q x 32k) * V^T frags (wave-local Ps, in-order per wave)
    __builtin_amdgcn_s_setprio(1);
    #pragma unroll
    for (int s = 0; s < 2; s++) {
      const half8 pa = *(const half8*)(Psb + q_loc * 128
                        + (((4 * s + lg) ^ (q_loc & 7)) << 4));
      #pragma unroll
      for (int df = 0; df < 4; df++) {
        const int vrow = df * 16 + ll;
        const half8 vb = *(const half8*)(Vsb + vrow * 128
                          + (((4 * s + lg) ^ (vrow & 7)) << 4));
        o[df] = __builtin_amdgcn_mfma_f32_16x16x32_f16(pa, vb, o[df], 0, 0, 0);
      }
    }
    __builtin_amdgcn_s_setprio(0);

    __syncthreads();   // drains this wave's stage issues; guards buffer reuse
  }

  // epilogue: gate/normalize, write over own q columns (disjoint across blocks)
  float lr[4];
  #pragma unroll
  for (int r = 0; r < 4; r++) lr[r] = __shfl(lrun, lg * 4 + r);
  #pragma unroll
  for (int r = 0; r < 4; r++) {
    const size_t qrow = qrow_g + lg * 4 + r;
    const float scale = ag[qrow * NHEADS + n] / lr[r];
    #pragma unroll
    for (int df = 0; df < 4; df++)
      qkv[qrow * 1536 + n * 64 + df * 16 + ll] = (_Float16)(o[df][r] * scale);
  }
}

extern "C" void kernel_launch(void* const* d_in, const int* in_sizes, int n_in,
                              void* d_out, int out_size, void* d_ws, size_t ws_size,
                              hipStream_t stream) {
  const float* x         = (const float*)d_in[0];
  const int*   token_ids = (const int*)d_in[1];
  // d_in[2] = mask (causal, analytic) — unused
  const float* w_q       = (const float*)d_in[3];
  const float* w_k       = (const float*)d_in[4];
  const float* w_v       = (const float*)d_in[5];
  const float* w_o       = (const float*)d_in[6];
  const float* ve_embed  = (const float*)d_in[7];
  const float* vlam      = (const float*)d_in[8];
  const float* velam     = (const float*)d_in[9];
  const float* ve_gate   = (const float*)d_in[10];
  const float* attn_gate = (const float*)d_in[11];
  float* out = (float*)d_out;

  // workspace carve-up (20.2 MB total)
  char* p = (char*)d_ws;
  _Float16* wqkvT = (_Float16*)p; p += (size_t)1536 * 1024 * 2;    // [wq|wk|wv]^T
  _Float16* woT   = (_Float16*)p; p += (size_t)1024 * 1024 * 2;
  _Float16* qkv   = (_Float16*)p; p += (size_t)4096 * 1536 * 2;    // [B*S][q1024|k256|v256]
  _Float16* vTb   = (_Float16*)p; p += (size_t)8 * 64 * S_LEN * 2; // [B*M][64][S]
  float*    ag    = (float*)p;    p += (size_t)4096 * NHEADS * 4;

  // x as f16, scratch-aliased into d_out (8.4 MB of 16.8 MB; dead before final GEMM
  // overwrites d_out — all launches are in-order on `stream`)
  _Float16* xh = (_Float16*)d_out;

  dim3 blk(256);
  transpose_all<<<dim3(640), blk, 0, stream>>>(w_q, w_k, w_v, w_o, wqkvT, woT);
  xcast<<<dim3(2048), blk, 0, stream>>>(x, xh);

  gemm_k<_Float16><<<dim3(12, 32), blk, 0, stream>>>(
      xh, wqkvT, qkv, 4096, 1536, 1024, 1024);

  prep_kernel<<<dim3(4096), blk, 0, stream>>>(x, token_ids, ve_embed, ve_gate,
                                              attn_gate, vlam, velam, qkv, ag);
  vtrans<<<dim3(32, 8), blk, 0, stream>>>(qkv, vTb);
  attn_mfma<<<dim3(1024), blk, 0, stream>>>(qkv, vTb, ag);

  gemm_k<float><<<dim3(8, 32), blk, 0, stream>>>(
      qkv, woT, out, 4096, 1024, 1024, 1536);
}